// Round 11
// baseline (1770.201 us; speedup 1.0000x reference)
//
#include <hip/hip_runtime.h>

#define N_NODES 50000
#define N_EDGES 800000
#define N_GRAPHS 128
#define IN_DIM 128
#define HID 256
#define H2 128
#define OUT_DIM 10
#define BN_EPS 1e-5f

#define NBKT 512                               // dst & 511 buckets
#define NSLOT 98                               // dst >> 9 slots (50000/512)
#define K1_ITEMS 4096
#define NB_EDGE ((N_EDGES + K1_ITEMS - 1) / K1_ITEMS)   // 196
#define BND_BLOCKS ((N_NODES + 255) / 256)     // 196
#define CW1_BLOCKS  ((IN_DIM * HID) / 256)     // 128
#define CW2_BLOCKS  ((HID * H2) / 256)         // 128
#define CW3_BLOCKS  ((H2 * H2) / 256)          // 64

typedef __attribute__((ext_vector_type(8))) short short8_t;   // 8 bf16 (4 VGPRs)
typedef __attribute__((ext_vector_type(4))) float f32x4;

__device__ __forceinline__ unsigned short f2bf(float f) {
    union { float f; unsigned u; } x; x.f = f;
    unsigned r = x.u + 0x7fffu + ((x.u >> 16) & 1u);   // round-to-nearest-even
    return (unsigned short)(r >> 16);
}
__device__ __forceinline__ float bf2f(unsigned short h) {
    union { unsigned u; float f; } x; x.u = ((unsigned)h) << 16;
    return x.f;
}
__device__ __forceinline__ unsigned pack2(float a, float b) {
    return (unsigned)f2bf(a) | ((unsigned)f2bf(b) << 16);
}

__device__ __forceinline__ void convw_body(const float* __restrict__ W,
        unsigned short* __restrict__ WT, int K, int NOUT, int i) {
    int k = i / NOUT, n = i - k * NOUT;
    WT[(size_t)n * K + k] = f2bf(W[i]);
}

// ---- K1: per-block LDS histograms of dst&511 / src&511 | convw x3 | graph bounds ----
__global__ __launch_bounds__(256) void k1_hist(const int* __restrict__ src,
        const int* __restrict__ dst, int* __restrict__ cntD, int* __restrict__ cntS,
        const float* __restrict__ W1, const float* __restrict__ W2, const float* __restrict__ W3,
        unsigned short* __restrict__ W1T, unsigned short* __restrict__ W2T,
        unsigned short* __restrict__ W3T,
        const int* __restrict__ gid, int* __restrict__ gstart) {
    int bid = blockIdx.x, tid = threadIdx.x;
    if (bid < NB_EDGE) {
        __shared__ int hD[NBKT], hS[NBKT];
        for (int i = tid; i < NBKT; i += 256) { hD[i] = 0; hS[i] = 0; }
        __syncthreads();
        int base = bid * K1_ITEMS;
#pragma unroll
        for (int it = 0; it < 16; it++) {
            int e = base + it * 256 + tid;
            if (e < N_EDGES) {
                atomicAdd(&hD[dst[e] & (NBKT - 1)], 1);
                atomicAdd(&hS[src[e] & (NBKT - 1)], 1);
            }
        }
        __syncthreads();
        for (int i = tid; i < NBKT; i += 256) {
            cntD[bid * NBKT + i] = hD[i];
            cntS[bid * NBKT + i] = hS[i];
        }
        return;
    }
    bid -= NB_EDGE;
    if (bid < CW1_BLOCKS) { convw_body(W1, W1T, IN_DIM, HID, bid * 256 + tid); return; }
    bid -= CW1_BLOCKS;
    if (bid < CW2_BLOCKS) { convw_body(W2, W2T, HID, H2, bid * 256 + tid); return; }
    bid -= CW2_BLOCKS;
    if (bid < CW3_BLOCKS) { convw_body(W3, W3T, H2, H2, bid * 256 + tid); return; }
    bid -= CW3_BLOCKS;
    {   // graph segment starts (graph_ids sorted)
        int n = bid * 256 + tid;
        if (n >= N_NODES) return;
        int g = gid[n];
        int gp = (n == 0) ? -1 : gid[n - 1];
        for (int k = gp + 1; k <= g; k++) gstart[k] = n;
        if (n == N_NODES - 1)
            for (int k = g + 1; k <= N_GRAPHS; k++) gstart[k] = N_NODES;
    }
}

// ---- K2: scan count tables -> per-(block,bucket) offsets + bucket bases ----
__global__ __launch_bounds__(512) void k2_scan(const int* __restrict__ cntD,
        const int* __restrict__ cntS, int* __restrict__ offD, int* __restrict__ offS,
        int* __restrict__ baseD, int* __restrict__ baseS) {
    int b = threadIdx.x;   // bucket 0..511
    int runD = 0, runS = 0;
    for (int blk = 0; blk < NB_EDGE; blk++) {
        int cD = cntD[blk * NBKT + b]; offD[blk * NBKT + b] = runD; runD += cD;
        int cS = cntS[blk * NBKT + b]; offS[blk * NBKT + b] = runS; runS += cS;
    }
    __shared__ int ldsD[NBKT], ldsS[NBKT];
    ldsD[b] = runD; ldsS[b] = runS;
    __syncthreads();
    for (int off = 1; off < NBKT; off <<= 1) {
        int uD = (b >= off) ? ldsD[b - off] : 0;
        int uS = (b >= off) ? ldsS[b - off] : 0;
        __syncthreads();
        ldsD[b] += uD; ldsS[b] += uS;
        __syncthreads();
    }
    baseD[b] = ldsD[b] - runD;
    baseS[b] = ldsS[b] - runS;
    if (b == NBKT - 1) { baseD[NBKT] = ldsD[b]; baseS[NBKT] = ldsS[b]; }
}

// ---- K3: scatter edges into dst-buckets (uint2{dst,src}) and src-buckets (src) ----
__global__ __launch_bounds__(256) void k3_scatter(const int* __restrict__ src,
        const int* __restrict__ dst, const int* __restrict__ offD, const int* __restrict__ offS,
        const int* __restrict__ baseD, const int* __restrict__ baseS,
        uint2* __restrict__ bufD, int* __restrict__ bufS) {
    __shared__ int cD[NBKT], cS[NBKT];
    int bid = blockIdx.x, tid = threadIdx.x;
    for (int i = tid; i < NBKT; i += 256) {
        cD[i] = baseD[i] + offD[bid * NBKT + i];
        cS[i] = baseS[i] + offS[bid * NBKT + i];
    }
    __syncthreads();
    int base = bid * K1_ITEMS;
#pragma unroll
    for (int it = 0; it < 16; it++) {
        int e = base + it * 256 + tid;
        if (e < N_EDGES) {
            int d = dst[e], s = src[e];
            int pd = atomicAdd(&cD[d & (NBKT - 1)], 1);
            bufD[pd] = make_uint2((unsigned)d, (unsigned)s);
            int ps = atomicAdd(&cS[s & (NBKT - 1)], 1);
            bufS[ps] = s;
        }
    }
}

// ---- K45: per dst-bucket indeg histogram | per src-bucket outdeg + n_feat prescale ----
__global__ __launch_bounds__(256) void k45_deg_prescale(const uint2* __restrict__ bufD,
        const int* __restrict__ baseD, int* __restrict__ indeg,
        const int* __restrict__ bufS, const int* __restrict__ baseS,
        const float* __restrict__ n_feat, int* __restrict__ outdeg,
        unsigned int* __restrict__ Xs) {
    int bid = blockIdx.x, t = threadIdx.x;
    if (bid < NBKT) {
        __shared__ int cnt[128];
        if (t < 128) cnt[t] = 0;
        __syncthreads();
        int b = bid, eb = baseD[b], ee = baseD[b + 1];
        for (int e = eb + t; e < ee; e += 256)
            atomicAdd(&cnt[bufD[e].x >> 9], 1);
        __syncthreads();
        if (t < NSLOT) {
            int node = t * NBKT + b;
            if (node < N_NODES) indeg[node] = cnt[t];
        }
        return;
    }
    {
        __shared__ int cnt[128];
        __shared__ float od[128];
        int b = bid - NBKT, eb = baseS[b], ee = baseS[b + 1];
        if (t < 128) cnt[t] = 0;
        __syncthreads();
        for (int e = eb + t; e < ee; e += 256)
            atomicAdd(&cnt[((unsigned)bufS[e]) >> 9], 1);
        __syncthreads();
        if (t < 128) od[t] = rsqrtf(fmaxf((float)cnt[t], 1.0f));
        if (t < NSLOT) {
            int node = t * NBKT + b;
            if (node < N_NODES) outdeg[node] = cnt[t];
        }
        __syncthreads();
        int pc = t & 127, rh = t >> 7;
        for (int slot = rh; slot < NSLOT; slot += 2) {
            int node = slot * NBKT + b;
            if (node < N_NODES) {
                float2 v = *reinterpret_cast<const float2*>(n_feat + (size_t)node * 128 + pc * 2);
                float s = od[slot];
                Xs[(size_t)node * 64 + pc] = pack2(v.x * s, v.y * s);
            }
        }
    }
}

// ---- edge-parallel aggregation: block = dst-bucket, f32 LDS accumulators ----
// acc layout swizzled: col c lives at slot (c&3)*32 + (c>>2) -> 4 ds_add ops per
// edge-pair hit banks 0..31 exactly 2-way (free). Paired rows: lanes 0-31 edge a,
// lanes 32-63 edge b; lane covers 4 consecutive bf16 cols (one uint2 gather).
// MODE 0: out = bf16(acc * id)
// MODE 1: out = bf16(relu(acc*id + bias) * od)   (pre-scales for next layer)
template<int MODE>
__global__ __launch_bounds__(1024) void edge_agg(const uint2* __restrict__ bufD,
        const int* __restrict__ baseD, const unsigned int* __restrict__ X,
        const int* __restrict__ indeg, const int* __restrict__ outdeg,
        const float* __restrict__ bias, unsigned int* __restrict__ out) {
    __shared__ float acc[NSLOT * 128];   // 50 KB
    int b = blockIdx.x;
    int t = threadIdx.x;
    for (int i = t; i < NSLOT * 128; i += 1024) acc[i] = 0.f;
    __syncthreads();
    int eb = baseD[b], ee = baseD[b + 1];
    int wave = t >> 6, lane = t & 63;
    int half = lane >> 5, l32 = lane & 31;
    int coff = l32 << 1;    // uint offset within 64-uint row

    for (int e0v = eb + wave * 16; e0v < ee; e0v += 16 * 16) {
        int e0 = __builtin_amdgcn_readfirstlane(e0v);   // wave-uniform -> s_loads
        int rem = ee - e0;
        if (rem >= 16) {
            uint2 u[8]; int slot[8];
#pragma unroll
            for (int q = 0; q < 8; q++) {
                uint2 pa = bufD[e0 + 2 * q];
                uint2 pb = bufD[e0 + 2 * q + 1];
                unsigned d = half ? pb.x : pa.x;
                unsigned s = half ? pb.y : pa.y;
                slot[q] = (int)(d >> 9);
                u[q] = *reinterpret_cast<const uint2*>(X + ((size_t)s << 6) + coff);
            }
#pragma unroll
            for (int q = 0; q < 8; q++) {
                float* bp = acc + slot[q] * 128;
                atomicAdd(bp + l32,      bf2f((unsigned short)(u[q].x & 0xffff)));
                atomicAdd(bp + 32 + l32, bf2f((unsigned short)(u[q].x >> 16)));
                atomicAdd(bp + 64 + l32, bf2f((unsigned short)(u[q].y & 0xffff)));
                atomicAdd(bp + 96 + l32, bf2f((unsigned short)(u[q].y >> 16)));
            }
        } else {
            int last = rem - 1;
            uint2 u[8]; int slot[8]; bool ok[8];
#pragma unroll
            for (int q = 0; q < 8; q++) {
                int ja = 2 * q, jb = ja + 1;
                uint2 pa = bufD[e0 + min(ja, last)];
                uint2 pb = bufD[e0 + min(jb, last)];
                unsigned d = half ? pb.x : pa.x;
                unsigned s = half ? pb.y : pa.y;
                int jj = half ? jb : ja;
                ok[q] = jj < rem;
                slot[q] = (int)(d >> 9);
                u[q] = *reinterpret_cast<const uint2*>(X + ((size_t)s << 6) + coff);
            }
#pragma unroll
            for (int q = 0; q < 8; q++) {
                unsigned vx = ok[q] ? u[q].x : 0u;   // bf16 0x0000 == 0.0f
                unsigned vy = ok[q] ? u[q].y : 0u;
                float* bp = acc + slot[q] * 128;
                atomicAdd(bp + l32,      bf2f((unsigned short)(vx & 0xffff)));
                atomicAdd(bp + 32 + l32, bf2f((unsigned short)(vx >> 16)));
                atomicAdd(bp + 64 + l32, bf2f((unsigned short)(vy & 0xffff)));
                atomicAdd(bp + 96 + l32, bf2f((unsigned short)(vy >> 16)));
            }
        }
    }
    __syncthreads();
    // write-out: thread covers (slot, col-quarter); 98*4 = 392 active threads
    int slot_o = t >> 2, qq = t & 3;
    if (slot_o < NSLOT) {
        int node = slot_o * NBKT + b;
        if (node < N_NODES) {
            float id = rsqrtf(fmaxf((float)indeg[node], 1.0f));
            float odv = (MODE == 1) ? rsqrtf(fmaxf((float)outdeg[node], 1.0f)) : 1.f;
            const float* bp = acc + slot_o * 128;
            unsigned pk[16];
#pragma unroll
            for (int m = 0; m < 16; m++) {
                int c0 = qq * 32 + 2 * m, c1 = c0 + 1;
                float v0 = bp[(c0 & 3) * 32 + (c0 >> 2)] * id;
                float v1 = bp[(c1 & 3) * 32 + (c1 >> 2)] * id;
                if (MODE == 1) {
                    v0 = fmaxf(v0 + bias[c0], 0.f) * odv;
                    v1 = fmaxf(v1 + bias[c1], 0.f) * odv;
                }
                pk[m] = pack2(v0, v1);
            }
            uint4* d4 = reinterpret_cast<uint4*>(out + (size_t)node * 64 + qq * 16);
#pragma unroll
            for (int m = 0; m < 4; m++)
                d4[m] = make_uint4(pk[4 * m], pk[4 * m + 1], pk[4 * m + 2], pk[4 * m + 3]);
        }
    }
}

// ---------------- MFMA bf16 GEMM, B-resident-in-registers, A streamed ----------------
// EPI 1: bias+relu (aux=bias[NOUT])   EPI 2: row-scale by rsqrt(outdeg) (auxi=outdeg)
// F32OUT: write float (numeric headroom for the pooled layer).
template<int K, int NOUT, int EPI, bool F32OUT>
__global__ __launch_bounds__(256) void mfma_gemm(const unsigned short* __restrict__ A,
        const unsigned short* __restrict__ WT, const float* __restrict__ aux,
        const int* __restrict__ auxi, void* __restrict__ outv) {
    constexpr int KK  = K / 32;
    constexpr int NBW = NOUT / 64;
    int wave = threadIdx.x >> 6;
    int lane = threadIdx.x & 63;
    int col0 = lane & 15;
    int kgrp = (lane >> 4) * 8;
    int wcol = wave * NBW * 16;

    short8_t b[NBW][KK];
    {
        const unsigned short* wbase = WT + (size_t)(wcol + col0) * K + kgrp;
#pragma unroll
        for (int n = 0; n < NBW; n++)
#pragma unroll
            for (int kk = 0; kk < KK; kk++)
                b[n][kk] = *reinterpret_cast<const short8_t*>(
                    wbase + (size_t)n * 16 * K + kk * 32);
    }
    float bv[NBW];
    if (EPI == 1) {
#pragma unroll
        for (int n = 0; n < NBW; n++) bv[n] = aux[wcol + n * 16 + col0];
    }

    constexpr int NT = N_NODES / 16;   // 3125 row tiles, exact
    for (int rt = blockIdx.x; rt < NT; rt += gridDim.x) {
        const unsigned short* ap = A + (size_t)(rt * 16 + col0) * K + kgrp;
        short8_t a[KK];
#pragma unroll
        for (int kk = 0; kk < KK; kk++)
            a[kk] = *reinterpret_cast<const short8_t*>(ap + kk * 32);

        f32x4 acc[NBW];
#pragma unroll
        for (int n = 0; n < NBW; n++) acc[n] = f32x4{0.f, 0.f, 0.f, 0.f};
#pragma unroll
        for (int kk = 0; kk < KK; kk++)
#pragma unroll
            for (int n = 0; n < NBW; n++)
                acc[n] = __builtin_amdgcn_mfma_f32_16x16x32_bf16(a[kk], b[n][kk], acc[n], 0, 0, 0);

        int rbase = rt * 16 + ((lane >> 4) << 2);
        float rs[4];
        if (EPI == 2) {
#pragma unroll
            for (int j = 0; j < 4; j++)
                rs[j] = rsqrtf(fmaxf((float)auxi[rbase + j], 1.0f));
        }
#pragma unroll
        for (int n = 0; n < NBW; n++) {
            int col = wcol + n * 16 + col0;
#pragma unroll
            for (int j = 0; j < 4; j++) {
                float v = acc[n][j];
                if (EPI == 1) v = fmaxf(v + bv[n], 0.f);
                if (EPI == 2) v = v * rs[j];
                if (F32OUT)
                    ((float*)outv)[(size_t)(rbase + j) * NOUT + col] = v;
                else
                    ((unsigned short*)outv)[(size_t)(rbase + j) * NOUT + col] = f2bf(v);
            }
        }
    }
}

// ---------------- sum pooling over contiguous segments (f32 in, f32 out) ----------
__global__ __launch_bounds__(512) void seg_pool(const float* __restrict__ X,
        const int* __restrict__ gstart, float* __restrict__ emb) {
    int g = blockIdx.x;
    int lane = threadIdx.x & 63;
    int stripe = threadIdx.x >> 6;
    int beg = gstart[g], end = gstart[g + 1];
    float ax = 0.f, ay = 0.f;
    for (int r = beg + stripe; r < end; r += 8) {
        float2 v = *reinterpret_cast<const float2*>(X + (size_t)r * 128 + lane * 2);
        ax += v.x; ay += v.y;
    }
    __shared__ float bufx[8][64], bufy[8][64];
    bufx[stripe][lane] = ax;
    bufy[stripe][lane] = ay;
    __syncthreads();
    if (stripe == 0) {
        float sx = 0.f, sy = 0.f;
#pragma unroll
        for (int q = 0; q < 8; q++) { sx += bufx[q][lane]; sy += bufy[q][lane]; }
        emb[g * 128 + lane * 2]     = sx;
        emb[g * 128 + lane * 2 + 1] = sy;
    }
}

// ---------------- fused BN + FC head + log_softmax ----------------
__global__ __launch_bounds__(128) void fc_kernel(const float* __restrict__ emb,
        const float* __restrict__ gamma, const float* __restrict__ beta,
        const float* __restrict__ Wf1, const float* __restrict__ bf1,
        const float* __restrict__ Wf2, const float* __restrict__ bf2,
        float* __restrict__ out_ls) {
    __shared__ float h[H2];
    __shared__ float logits[OUT_DIM];
    int g = blockIdx.x;
    int j = threadIdx.x;
    float s = 0.f;
    for (int q = 0; q < N_GRAPHS; q++) s += emb[q * 128 + j];
    float mean = s * (1.0f / N_GRAPHS);
    float v = 0.f;
    for (int q = 0; q < N_GRAPHS; q++) {
        float d = emb[q * 128 + j] - mean;
        v += d * d;
    }
    v *= (1.0f / N_GRAPHS);
    float scale = rsqrtf(v + BN_EPS) * gamma[j];
    h[j] = (emb[g * 128 + j] - mean) * scale + beta[j];
    __syncthreads();
    float acc = bf1[j];
    for (int k = 0; k < H2; k++) acc += h[k] * Wf1[k * H2 + j];
    __syncthreads();
    h[j] = fmaxf(acc, 0.f);
    __syncthreads();
    if (j < OUT_DIM) {
        float a2 = bf2[j];
        for (int k = 0; k < H2; k++) a2 += h[k] * Wf2[k * OUT_DIM + j];
        logits[j] = a2;
    }
    __syncthreads();
    if (j < OUT_DIM) {
        float m = -1e30f;
        for (int o = 0; o < OUT_DIM; o++) m = fmaxf(m, logits[o]);
        float se = 0.f;
        for (int o = 0; o < OUT_DIM; o++) se += expf(logits[o] - m);
        out_ls[g * OUT_DIM + j] = logits[j] - m - logf(se);
    }
}

extern "C" void kernel_launch(void* const* d_in, const int* in_sizes, int n_in,
                              void* d_out, int out_size, void* d_ws, size_t ws_size,
                              hipStream_t stream) {
    const float* n_feat = (const float*)d_in[0];
    const int*   src    = (const int*)d_in[1];
    const int*   dst    = (const int*)d_in[2];
    const int*   gid    = (const int*)d_in[3];
    const float* W1     = (const float*)d_in[4];
    const float* b1     = (const float*)d_in[5];
    const float* W2     = (const float*)d_in[6];
    const float* b2     = (const float*)d_in[7];
    const float* W3     = (const float*)d_in[8];
    const float* b3     = (const float*)d_in[9];
    const float* Wf1    = (const float*)d_in[10];
    const float* bf1    = (const float*)d_in[11];
    const float* Wf2    = (const float*)d_in[12];
    const float* bf2    = (const float*)d_in[13];
    const float* gamma  = (const float*)d_in[14];
    const float* beta   = (const float*)d_in[15];
    float* out = (float*)d_out;

    char* ws = (char*)d_ws;
    size_t off = 0;
    auto alloc = [&](size_t bytes) {
        void* p = ws + off;
        off = (off + bytes + 255) & ~(size_t)255;
        return p;
    };
    int* cntD    = (int*)alloc((size_t)NB_EDGE * NBKT * 4);
    int* cntS    = (int*)alloc((size_t)NB_EDGE * NBKT * 4);
    int* offD    = (int*)alloc((size_t)NB_EDGE * NBKT * 4);
    int* offS    = (int*)alloc((size_t)NB_EDGE * NBKT * 4);
    int* baseD   = (int*)alloc((NBKT + 1) * 4);
    int* baseS   = (int*)alloc((NBKT + 1) * 4);
    int* indeg   = (int*)alloc((size_t)N_NODES * 4);
    int* outdeg  = (int*)alloc((size_t)N_NODES * 4);
    int* gstart  = (int*)alloc((size_t)(N_GRAPHS + 1) * 4);
    uint2* bufD  = (uint2*)alloc((size_t)N_EDGES * 8);
    int* bufS    = (int*)alloc((size_t)N_EDGES * 4);
    unsigned short* Xs  = (unsigned short*)alloc((size_t)N_NODES * 128 * 2);
    unsigned short* A   = (unsigned short*)alloc((size_t)N_NODES * 128 * 2);
    unsigned short* B   = (unsigned short*)alloc((size_t)N_NODES * 256 * 2);  // also f32 [N,128]
    unsigned short* W1T = (unsigned short*)alloc((size_t)IN_DIM * HID * 2);
    unsigned short* W2T = (unsigned short*)alloc((size_t)HID * H2 * 2);
    unsigned short* W3T = (unsigned short*)alloc((size_t)H2 * H2 * 2);
    float* Bf32 = (float*)B;   // N*256*2 bytes == N*128*4 bytes

    // preprocessing: zero global atomics, no CSR needed (edge-parallel aggs)
    k1_hist<<<NB_EDGE + CW1_BLOCKS + CW2_BLOCKS + CW3_BLOCKS + BND_BLOCKS, 256, 0, stream>>>(
        src, dst, cntD, cntS, W1, W2, W3, W1T, W2T, W3T, gid, gstart);
    k2_scan<<<1, 512, 0, stream>>>(cntD, cntS, offD, offS, baseD, baseS);
    k3_scatter<<<NB_EDGE, 256, 0, stream>>>(src, dst, offD, offS, baseD, baseS, bufD, bufS);
    k45_deg_prescale<<<NBKT * 2, 256, 0, stream>>>(bufD, baseD, indeg,
                                                   bufS, baseS, n_feat, outdeg,
                                                   (unsigned int*)Xs);

    const int GEMM_GRID = 1024;

    // Layer 1: A = bf16(agg(Xs)·id); B = bf16(relu(A@W1 + b1))  [N,256]
    edge_agg<0><<<NBKT, 1024, 0, stream>>>(bufD, baseD, (unsigned int*)Xs,
                                           indeg, outdeg, nullptr, (unsigned int*)A);
    mfma_gemm<128, 256, 1, false><<<GEMM_GRID, 256, 0, stream>>>(A, W1T, b1, nullptr, B);

    // Layer 2: A = bf16((X1@W2)·od); B = bf16(relu(agg(A)·id + b2)·od)
    mfma_gemm<256, 128, 2, false><<<GEMM_GRID, 256, 0, stream>>>(B, W2T, nullptr, outdeg, A);
    edge_agg<1><<<NBKT, 1024, 0, stream>>>(bufD, baseD, (unsigned int*)A,
                                           indeg, outdeg, b2, (unsigned int*)B);

    // Layer 3: A = bf16(agg(B)·id); Bf32 = relu(A@W3 + b3)  [f32 for pooling accuracy]
    edge_agg<0><<<NBKT, 1024, 0, stream>>>(bufD, baseD, (unsigned int*)B,
                                           indeg, outdeg, nullptr, (unsigned int*)A);
    mfma_gemm<128, 128, 1, true><<<GEMM_GRID, 256, 0, stream>>>(A, W3T, b3, nullptr, Bf32);

    // Readout
    seg_pool<<<N_GRAPHS, 512, 0, stream>>>(Bf32, gstart, out);
    fc_kernel<<<N_GRAPHS, 128, 0, stream>>>(out, gamma, beta, Wf1, bf1, Wf2, bf2,
                                            out + (size_t)N_GRAPHS * H2);
}

// Round 12
// 344.103 us; speedup vs baseline: 5.1444x; 5.1444x over previous
//
#include <hip/hip_runtime.h>

#define N_NODES 50000
#define N_EDGES 800000
#define N_GRAPHS 128
#define IN_DIM 128
#define HID 256
#define H2 128
#define OUT_DIM 10
#define BN_EPS 1e-5f

#define DBKT 8192                              // dst & 8191 buckets (~98 edges each)
#define DSLOT 7                                // dst >> 13 slots (50000/8192 -> 0..6)
#define SBKT 512                               // src & 511 buckets
#define K1_ITEMS 4096
#define NB_EDGE ((N_EDGES + K1_ITEMS - 1) / K1_ITEMS)   // 196
#define BND_BLOCKS ((N_NODES + 255) / 256)     // 196
#define CW1_BLOCKS  ((IN_DIM * HID) / 256)     // 128
#define CW2_BLOCKS  ((HID * H2) / 256)         // 128
#define CW3_BLOCKS  ((H2 * H2) / 256)          // 64

typedef __attribute__((ext_vector_type(8))) short short8_t;   // 8 bf16 (4 VGPRs)
typedef __attribute__((ext_vector_type(4))) float f32x4;

__device__ __forceinline__ unsigned short f2bf(float f) {
    union { float f; unsigned u; } x; x.f = f;
    unsigned r = x.u + 0x7fffu + ((x.u >> 16) & 1u);   // round-to-nearest-even
    return (unsigned short)(r >> 16);
}
__device__ __forceinline__ float bf2f(unsigned short h) {
    union { unsigned u; float f; } x; x.u = ((unsigned)h) << 16;
    return x.f;
}
__device__ __forceinline__ unsigned pack2(float a, float b) {
    return (unsigned)f2bf(a) | ((unsigned)f2bf(b) << 16);
}

__device__ __forceinline__ void convw_body(const float* __restrict__ W,
        unsigned short* __restrict__ WT, int K, int NOUT, int i) {
    int k = i / NOUT, n = i - k * NOUT;
    WT[(size_t)n * K + k] = f2bf(W[i]);
}

// ---- K1: per-block LDS hist of dst&8191 and src&511 | convw x3 | graph bounds ----
__global__ __launch_bounds__(256) void k1_hist(const int* __restrict__ src,
        const int* __restrict__ dst, int* __restrict__ cntD, int* __restrict__ cntS,
        const float* __restrict__ W1, const float* __restrict__ W2, const float* __restrict__ W3,
        unsigned short* __restrict__ W1T, unsigned short* __restrict__ W2T,
        unsigned short* __restrict__ W3T,
        const int* __restrict__ gid, int* __restrict__ gstart) {
    int bid = blockIdx.x, tid = threadIdx.x;
    if (bid < NB_EDGE) {
        __shared__ int hD[DBKT];
        __shared__ int hS[SBKT];
        for (int i = tid; i < DBKT; i += 256) hD[i] = 0;
        for (int i = tid; i < SBKT; i += 256) hS[i] = 0;
        __syncthreads();
        int base = bid * K1_ITEMS;
#pragma unroll
        for (int it = 0; it < 16; it++) {
            int e = base + it * 256 + tid;
            if (e < N_EDGES) {
                atomicAdd(&hD[dst[e] & (DBKT - 1)], 1);
                atomicAdd(&hS[src[e] & (SBKT - 1)], 1);
            }
        }
        __syncthreads();
        for (int i = tid; i < DBKT; i += 256) cntD[(size_t)bid * DBKT + i] = hD[i];
        for (int i = tid; i < SBKT; i += 256) cntS[(size_t)bid * SBKT + i] = hS[i];
        return;
    }
    bid -= NB_EDGE;
    if (bid < CW1_BLOCKS) { convw_body(W1, W1T, IN_DIM, HID, bid * 256 + tid); return; }
    bid -= CW1_BLOCKS;
    if (bid < CW2_BLOCKS) { convw_body(W2, W2T, HID, H2, bid * 256 + tid); return; }
    bid -= CW2_BLOCKS;
    if (bid < CW3_BLOCKS) { convw_body(W3, W3T, H2, H2, bid * 256 + tid); return; }
    bid -= CW3_BLOCKS;
    {   // graph segment starts (graph_ids sorted)
        int n = bid * 256 + tid;
        if (n >= N_NODES) return;
        int g = gid[n];
        int gp = (n == 0) ? -1 : gid[n - 1];
        for (int k = gp + 1; k <= g; k++) gstart[k] = n;
        if (n == N_NODES - 1)
            for (int k = g + 1; k <= N_GRAPHS; k++) gstart[k] = N_NODES;
    }
}

// ---- K2d: dst-bucket scan, 8 chunks of 1024 buckets (chunk-local bases) ----
__global__ __launch_bounds__(1024) void k2d_scan(const int* __restrict__ cntD,
        int* __restrict__ offD, int* __restrict__ baseD, int* __restrict__ dtot) {
    int t = threadIdx.x;
    int b = blockIdx.x * 1024 + t;
    int run = 0;
    for (int blk = 0; blk < NB_EDGE; blk++) {
        int c = cntD[(size_t)blk * DBKT + b];
        offD[(size_t)blk * DBKT + b] = run;
        run += c;
    }
    __shared__ int lds[1024];
    lds[t] = run;
    __syncthreads();
    for (int off = 1; off < 1024; off <<= 1) {
        int u = (t >= off) ? lds[t - off] : 0;
        __syncthreads();
        lds[t] += u;
        __syncthreads();
    }
    baseD[b] = lds[t] - run;
    if (t == 1023) dtot[blockIdx.x] = lds[t];
}

// ---- K2s: src-bucket scan (single block) ----
__global__ __launch_bounds__(512) void k2s_scan(const int* __restrict__ cntS,
        int* __restrict__ offS, int* __restrict__ baseS) {
    int b = threadIdx.x;
    int run = 0;
    for (int blk = 0; blk < NB_EDGE; blk++) {
        int c = cntS[(size_t)blk * SBKT + b];
        offS[(size_t)blk * SBKT + b] = run;
        run += c;
    }
    __shared__ int lds[512];
    lds[b] = run;
    __syncthreads();
    for (int off = 1; off < 512; off <<= 1) {
        int u = (b >= off) ? lds[b - off] : 0;
        __syncthreads();
        lds[b] += u;
        __syncthreads();
    }
    baseS[b] = lds[b] - run;
    if (b == 511) baseS[SBKT] = lds[b];
}

// ---- K2fix: add chunk prefix to baseD ----
__global__ __launch_bounds__(1024) void k2fix(const int* __restrict__ dtot,
                                              int* __restrict__ baseD) {
    __shared__ int off[8];
    if (threadIdx.x == 0) {
        int r = 0;
        for (int i = 0; i < 8; i++) { off[i] = r; r += dtot[i]; }
    }
    __syncthreads();
    for (int i = threadIdx.x; i < DBKT; i += 1024) baseD[i] += off[i >> 10];
    if (threadIdx.x == 0) baseD[DBKT] = N_EDGES;
}

// ---- K3: scatter edges into dst-buckets (uint2{dst,src}) and src-buckets (src) ----
__global__ __launch_bounds__(256) void k3_scatter(const int* __restrict__ src,
        const int* __restrict__ dst, const int* __restrict__ offD, const int* __restrict__ offS,
        const int* __restrict__ baseD, const int* __restrict__ baseS,
        uint2* __restrict__ bufD, int* __restrict__ bufS) {
    __shared__ int cD[DBKT];
    __shared__ int cS[SBKT];
    int bid = blockIdx.x, tid = threadIdx.x;
    for (int i = tid; i < DBKT; i += 256) cD[i] = baseD[i] + offD[(size_t)bid * DBKT + i];
    for (int i = tid; i < SBKT; i += 256) cS[i] = baseS[i] + offS[(size_t)bid * SBKT + i];
    __syncthreads();
    int base = bid * K1_ITEMS;
#pragma unroll
    for (int it = 0; it < 16; it++) {
        int e = base + it * 256 + tid;
        if (e < N_EDGES) {
            int d = dst[e], s = src[e];
            int pd = atomicAdd(&cD[d & (DBKT - 1)], 1);
            bufD[pd] = make_uint2((unsigned)d, (unsigned)s);
            int ps = atomicAdd(&cS[s & (SBKT - 1)], 1);
            bufS[ps] = s;
        }
    }
}

// ---- K5: per src-bucket outdeg histogram + fused n_feat prescale -> Xs bf16 ----
__global__ __launch_bounds__(256) void k5_outdeg_prescale(const int* __restrict__ bufS,
        const int* __restrict__ baseS, const float* __restrict__ n_feat,
        int* __restrict__ outdeg, unsigned int* __restrict__ Xs) {
    __shared__ int cnt[128];
    __shared__ float od[128];
    int b = blockIdx.x, t = threadIdx.x;
    int eb = baseS[b], ee = baseS[b + 1];
    if (t < 128) cnt[t] = 0;
    __syncthreads();
    for (int e = eb + t; e < ee; e += 256)
        atomicAdd(&cnt[((unsigned)bufS[e]) >> 9], 1);
    __syncthreads();
    if (t < 128) od[t] = rsqrtf(fmaxf((float)cnt[t], 1.0f));
    if (t < 98) {
        int node = t * SBKT + b;
        if (node < N_NODES) outdeg[node] = cnt[t];
    }
    __syncthreads();
    int pc = t & 127, rh = t >> 7;
    for (int slot = rh; slot < 98; slot += 2) {
        int node = slot * SBKT + b;
        if (node < N_NODES) {
            float2 v = *reinterpret_cast<const float2*>(n_feat + (size_t)node * 128 + pc * 2);
            float s = od[slot];
            Xs[(size_t)node * 64 + pc] = pack2(v.x * s, v.y * s);
        }
    }
}

// ---- edge-parallel aggregation: wave = dst-bucket, VGPR accumulators, no atomics ----
// Wave processes one edge at a time: 64 lanes read the full 256B source row
// (full-line utilization); 8 gathers in flight; edge records broadcast via
// readlane; slot (dst>>13, wave-uniform scalar) dispatched by switch.
// indeg counted inline (dc[s]).
// MODE 0: out = bf16(acc * id)
// MODE 1: out = bf16(relu(acc*id + bias) * od)   (pre-scales for next layer)
template<int MODE>
__global__ __launch_bounds__(256) void edge_agg(const uint2* __restrict__ bufD,
        const int* __restrict__ baseD, const unsigned int* __restrict__ X,
        const int* __restrict__ outdeg, const float* __restrict__ bias,
        unsigned int* __restrict__ out) {
    int wave = threadIdx.x >> 6, lane = threadIdx.x & 63;
    int bkt = blockIdx.x * 4 + wave;                  // 0..8191
    int eb = __builtin_amdgcn_readfirstlane(baseD[bkt]);
    int ee = __builtin_amdgcn_readfirstlane(baseD[bkt + 1]);

    float ax[DSLOT], ay[DSLOT];
    int dc[DSLOT];
#pragma unroll
    for (int s = 0; s < DSLOT; s++) { ax[s] = 0.f; ay[s] = 0.f; dc[s] = 0; }

    for (int e0 = eb; e0 < ee; e0 += 64) {
        int m = ee - e0; if (m > 64) m = 64;
        uint2 rec = bufD[e0 + min(lane, m - 1)];
        for (int j0 = 0; j0 < m; j0 += 8) {
            unsigned uu[8]; int sl[8];
#pragma unroll
            for (int q = 0; q < 8; q++) {
                int jj = j0 + q; if (jj > m - 1) jj = m - 1;
                unsigned d = __shfl(rec.x, jj);
                unsigned s = __shfl(rec.y, jj);
                sl[q] = __builtin_amdgcn_readfirstlane((int)(d >> 13));
                uu[q] = X[((size_t)s << 6) + lane];
            }
#pragma unroll
            for (int q = 0; q < 8; q++) {
                if (j0 + q < m) {                       // wave-uniform predicate
                    float vx = bf2f((unsigned short)(uu[q] & 0xffff));
                    float vy = bf2f((unsigned short)(uu[q] >> 16));
                    switch (sl[q]) {                    // scalar jump (uniform)
                    case 0: ax[0] += vx; ay[0] += vy; dc[0]++; break;
                    case 1: ax[1] += vx; ay[1] += vy; dc[1]++; break;
                    case 2: ax[2] += vx; ay[2] += vy; dc[2]++; break;
                    case 3: ax[3] += vx; ay[3] += vy; dc[3]++; break;
                    case 4: ax[4] += vx; ay[4] += vy; dc[4]++; break;
                    case 5: ax[5] += vx; ay[5] += vy; dc[5]++; break;
                    default: ax[6] += vx; ay[6] += vy; dc[6]++; break;
                    }
                }
            }
        }
    }

#pragma unroll
    for (int s = 0; s < DSLOT; s++) {
        int node = (s << 13) + bkt;
        if (node < N_NODES) {
            float id = rsqrtf(fmaxf((float)dc[s], 1.0f));
            float v0 = ax[s] * id, v1 = ay[s] * id;
            if (MODE == 1) {
                float odv = rsqrtf(fmaxf((float)outdeg[node], 1.0f));
                v0 = fmaxf(v0 + bias[lane * 2], 0.f) * odv;
                v1 = fmaxf(v1 + bias[lane * 2 + 1], 0.f) * odv;
            }
            out[(size_t)node * 64 + lane] = pack2(v0, v1);
        }
    }
}

// ---------------- MFMA bf16 GEMM, B-resident-in-registers, A streamed ----------------
// EPI 1: bias+relu (aux=bias[NOUT])   EPI 2: row-scale by rsqrt(outdeg) (auxi=outdeg)
// F32OUT: write float (numeric headroom for the pooled layer).
template<int K, int NOUT, int EPI, bool F32OUT>
__global__ __launch_bounds__(256) void mfma_gemm(const unsigned short* __restrict__ A,
        const unsigned short* __restrict__ WT, const float* __restrict__ aux,
        const int* __restrict__ auxi, void* __restrict__ outv) {
    constexpr int KK  = K / 32;
    constexpr int NBW = NOUT / 64;
    int wave = threadIdx.x >> 6;
    int lane = threadIdx.x & 63;
    int col0 = lane & 15;
    int kgrp = (lane >> 4) * 8;
    int wcol = wave * NBW * 16;

    short8_t b[NBW][KK];
    {
        const unsigned short* wbase = WT + (size_t)(wcol + col0) * K + kgrp;
#pragma unroll
        for (int n = 0; n < NBW; n++)
#pragma unroll
            for (int kk = 0; kk < KK; kk++)
                b[n][kk] = *reinterpret_cast<const short8_t*>(
                    wbase + (size_t)n * 16 * K + kk * 32);
    }
    float bv[NBW];
    if (EPI == 1) {
#pragma unroll
        for (int n = 0; n < NBW; n++) bv[n] = aux[wcol + n * 16 + col0];
    }

    constexpr int NT = N_NODES / 16;   // 3125 row tiles, exact
    for (int rt = blockIdx.x; rt < NT; rt += gridDim.x) {
        const unsigned short* ap = A + (size_t)(rt * 16 + col0) * K + kgrp;
        short8_t a[KK];
#pragma unroll
        for (int kk = 0; kk < KK; kk++)
            a[kk] = *reinterpret_cast<const short8_t*>(ap + kk * 32);

        f32x4 acc[NBW];
#pragma unroll
        for (int n = 0; n < NBW; n++) acc[n] = f32x4{0.f, 0.f, 0.f, 0.f};
#pragma unroll
        for (int kk = 0; kk < KK; kk++)
#pragma unroll
            for (int n = 0; n < NBW; n++)
                acc[n] = __builtin_amdgcn_mfma_f32_16x16x32_bf16(a[kk], b[n][kk], acc[n], 0, 0, 0);

        int rbase = rt * 16 + ((lane >> 4) << 2);
        float rs[4];
        if (EPI == 2) {
#pragma unroll
            for (int j = 0; j < 4; j++)
                rs[j] = rsqrtf(fmaxf((float)auxi[rbase + j], 1.0f));
        }
#pragma unroll
        for (int n = 0; n < NBW; n++) {
            int col = wcol + n * 16 + col0;
#pragma unroll
            for (int j = 0; j < 4; j++) {
                float v = acc[n][j];
                if (EPI == 1) v = fmaxf(v + bv[n], 0.f);
                if (EPI == 2) v = v * rs[j];
                if (F32OUT)
                    ((float*)outv)[(size_t)(rbase + j) * NOUT + col] = v;
                else
                    ((unsigned short*)outv)[(size_t)(rbase + j) * NOUT + col] = f2bf(v);
            }
        }
    }
}

// ---------------- sum pooling over contiguous segments (f32 in, f32 out) ----------
__global__ __launch_bounds__(512) void seg_pool(const float* __restrict__ X,
        const int* __restrict__ gstart, float* __restrict__ emb) {
    int g = blockIdx.x;
    int lane = threadIdx.x & 63;
    int stripe = threadIdx.x >> 6;
    int beg = gstart[g], end = gstart[g + 1];
    float ax = 0.f, ay = 0.f;
    for (int r = beg + stripe; r < end; r += 8) {
        float2 v = *reinterpret_cast<const float2*>(X + (size_t)r * 128 + lane * 2);
        ax += v.x; ay += v.y;
    }
    __shared__ float bufx[8][64], bufy[8][64];
    bufx[stripe][lane] = ax;
    bufy[stripe][lane] = ay;
    __syncthreads();
    if (stripe == 0) {
        float sx = 0.f, sy = 0.f;
#pragma unroll
        for (int q = 0; q < 8; q++) { sx += bufx[q][lane]; sy += bufy[q][lane]; }
        emb[g * 128 + lane * 2]     = sx;
        emb[g * 128 + lane * 2 + 1] = sy;
    }
}

// ---------------- fused BN + FC head + log_softmax ----------------
__global__ __launch_bounds__(128) void fc_kernel(const float* __restrict__ emb,
        const float* __restrict__ gamma, const float* __restrict__ beta,
        const float* __restrict__ Wf1, const float* __restrict__ bf1,
        const float* __restrict__ Wf2, const float* __restrict__ bf2,
        float* __restrict__ out_ls) {
    __shared__ float h[H2];
    __shared__ float logits[OUT_DIM];
    int g = blockIdx.x;
    int j = threadIdx.x;
    float s = 0.f;
    for (int q = 0; q < N_GRAPHS; q++) s += emb[q * 128 + j];
    float mean = s * (1.0f / N_GRAPHS);
    float v = 0.f;
    for (int q = 0; q < N_GRAPHS; q++) {
        float d = emb[q * 128 + j] - mean;
        v += d * d;
    }
    v *= (1.0f / N_GRAPHS);
    float scale = rsqrtf(v + BN_EPS) * gamma[j];
    h[j] = (emb[g * 128 + j] - mean) * scale + beta[j];
    __syncthreads();
    float acc = bf1[j];
    for (int k = 0; k < H2; k++) acc += h[k] * Wf1[k * H2 + j];
    __syncthreads();
    h[j] = fmaxf(acc, 0.f);
    __syncthreads();
    if (j < OUT_DIM) {
        float a2 = bf2[j];
        for (int k = 0; k < H2; k++) a2 += h[k] * Wf2[k * OUT_DIM + j];
        logits[j] = a2;
    }
    __syncthreads();
    if (j < OUT_DIM) {
        float m = -1e30f;
        for (int o = 0; o < OUT_DIM; o++) m = fmaxf(m, logits[o]);
        float se = 0.f;
        for (int o = 0; o < OUT_DIM; o++) se += expf(logits[o] - m);
        out_ls[g * OUT_DIM + j] = logits[j] - m - logf(se);
    }
}

extern "C" void kernel_launch(void* const* d_in, const int* in_sizes, int n_in,
                              void* d_out, int out_size, void* d_ws, size_t ws_size,
                              hipStream_t stream) {
    const float* n_feat = (const float*)d_in[0];
    const int*   src    = (const int*)d_in[1];
    const int*   dst    = (const int*)d_in[2];
    const int*   gid    = (const int*)d_in[3];
    const float* W1     = (const float*)d_in[4];
    const float* b1     = (const float*)d_in[5];
    const float* W2     = (const float*)d_in[6];
    const float* b2     = (const float*)d_in[7];
    const float* W3     = (const float*)d_in[8];
    const float* b3     = (const float*)d_in[9];
    const float* Wf1    = (const float*)d_in[10];
    const float* bf1    = (const float*)d_in[11];
    const float* Wf2    = (const float*)d_in[12];
    const float* bf2    = (const float*)d_in[13];
    const float* gamma  = (const float*)d_in[14];
    const float* beta   = (const float*)d_in[15];
    float* out = (float*)d_out;

    char* ws = (char*)d_ws;
    size_t off = 0;
    auto alloc = [&](size_t bytes) {
        void* p = ws + off;
        off = (off + bytes + 255) & ~(size_t)255;
        return p;
    };
    int* cntD    = (int*)alloc((size_t)NB_EDGE * DBKT * 4);
    int* offD    = (int*)alloc((size_t)NB_EDGE * DBKT * 4);
    int* cntS    = (int*)alloc((size_t)NB_EDGE * SBKT * 4);
    int* offS    = (int*)alloc((size_t)NB_EDGE * SBKT * 4);
    int* baseD   = (int*)alloc((DBKT + 1) * 4);
    int* baseS   = (int*)alloc((SBKT + 1) * 4);
    int* dtot    = (int*)alloc(8 * 4);
    int* outdeg  = (int*)alloc((size_t)N_NODES * 4);
    int* gstart  = (int*)alloc((size_t)(N_GRAPHS + 1) * 4);
    uint2* bufD  = (uint2*)alloc((size_t)N_EDGES * 8);
    int* bufS    = (int*)alloc((size_t)N_EDGES * 4);
    unsigned short* Xs  = (unsigned short*)alloc((size_t)N_NODES * 128 * 2);
    unsigned short* A   = (unsigned short*)alloc((size_t)N_NODES * 128 * 2);
    unsigned short* B   = (unsigned short*)alloc((size_t)N_NODES * 256 * 2);  // also f32 [N,128]
    unsigned short* W1T = (unsigned short*)alloc((size_t)IN_DIM * HID * 2);
    unsigned short* W2T = (unsigned short*)alloc((size_t)HID * H2 * 2);
    unsigned short* W3T = (unsigned short*)alloc((size_t)H2 * H2 * 2);
    float* Bf32 = (float*)B;   // N*256*2 bytes == N*128*4 bytes

    // preprocessing: zero global atomics, no CSR (edge-parallel reg-acc aggs)
    k1_hist<<<NB_EDGE + CW1_BLOCKS + CW2_BLOCKS + CW3_BLOCKS + BND_BLOCKS, 256, 0, stream>>>(
        src, dst, cntD, cntS, W1, W2, W3, W1T, W2T, W3T, gid, gstart);
    k2d_scan<<<8, 1024, 0, stream>>>(cntD, offD, baseD, dtot);
    k2s_scan<<<1, 512, 0, stream>>>(cntS, offS, baseS);
    k2fix<<<1, 1024, 0, stream>>>(dtot, baseD);
    k3_scatter<<<NB_EDGE, 256, 0, stream>>>(src, dst, offD, offS, baseD, baseS, bufD, bufS);
    k5_outdeg_prescale<<<SBKT, 256, 0, stream>>>(bufS, baseS, n_feat, outdeg,
                                                 (unsigned int*)Xs);

    const int AGG_GRID = DBKT / 4;   // 2048 blocks x 4 waves = 8192 buckets
    const int GEMM_GRID = 1024;

    // Layer 1: A = bf16(agg(Xs)·id); B = bf16(relu(A@W1 + b1))  [N,256]
    edge_agg<0><<<AGG_GRID, 256, 0, stream>>>(bufD, baseD, (unsigned int*)Xs,
                                              outdeg, nullptr, (unsigned int*)A);
    mfma_gemm<128, 256, 1, false><<<GEMM_GRID, 256, 0, stream>>>(A, W1T, b1, nullptr, B);

    // Layer 2: A = bf16((X1@W2)·od); B = bf16(relu(agg(A)·id + b2)·od)
    mfma_gemm<256, 128, 2, false><<<GEMM_GRID, 256, 0, stream>>>(B, W2T, nullptr, outdeg, A);
    edge_agg<1><<<AGG_GRID, 256, 0, stream>>>(bufD, baseD, (unsigned int*)A,
                                              outdeg, b2, (unsigned int*)B);

    // Layer 3: A = bf16(agg(B)·id); Bf32 = relu(A@W3 + b3)  [f32 for pooling accuracy]
    edge_agg<0><<<AGG_GRID, 256, 0, stream>>>(bufD, baseD, (unsigned int*)B,
                                              outdeg, nullptr, (unsigned int*)A);
    mfma_gemm<128, 128, 1, true><<<GEMM_GRID, 256, 0, stream>>>(A, W3T, b3, nullptr, Bf32);

    // Readout
    seg_pool<<<N_GRAPHS, 512, 0, stream>>>(Bf32, gstart, out);
    fc_kernel<<<N_GRAPHS, 128, 0, stream>>>(out, gamma, beta, Wf1, bf1, Wf2, bf2,
                                            out + (size_t)N_GRAPHS * H2);
}

// Round 13
// 255.445 us; speedup vs baseline: 6.9299x; 1.3471x over previous
//
#include <hip/hip_runtime.h>

#define N_NODES 50000
#define N_EDGES 800000
#define N_GRAPHS 128
#define IN_DIM 128
#define HID 256
#define H2 128
#define OUT_DIM 10
#define BN_EPS 1e-5f

#define NBUCK 196                              // dst>>8 buckets (50000/256)
#define K1_ITEMS 2048
#define NB_EDGE ((N_EDGES + K1_ITEMS - 1) / K1_ITEMS)   // 391
#define BND_BLOCKS ((N_NODES + 255) / 256)     // 196
#define CW1_BLOCKS  ((IN_DIM * HID) / 256)     // 128
#define CW2_BLOCKS  ((HID * H2) / 256)         // 128
#define CW3_BLOCKS  ((H2 * H2) / 256)          // 64

typedef __attribute__((ext_vector_type(8))) short short8_t;   // 8 bf16 (4 VGPRs)
typedef __attribute__((ext_vector_type(4))) float f32x4;

__device__ __forceinline__ unsigned short f2bf(float f) {
    union { float f; unsigned u; } x; x.f = f;
    unsigned r = x.u + 0x7fffu + ((x.u >> 16) & 1u);   // round-to-nearest-even
    return (unsigned short)(r >> 16);
}
__device__ __forceinline__ float bf2f(unsigned short h) {
    union { unsigned u; float f; } x; x.u = ((unsigned)h) << 16;
    return x.f;
}
__device__ __forceinline__ unsigned pack2(float a, float b) {
    return (unsigned)f2bf(a) | ((unsigned)f2bf(b) << 16);
}

__device__ __forceinline__ void convw_body(const float* __restrict__ W,
        unsigned short* __restrict__ WT, int K, int NOUT, int i) {
    int k = i / NOUT, n = i - k * NOUT;
    WT[(size_t)n * K + k] = f2bf(W[i]);
}

// ---- K1: per-block LDS histograms of dst>>8 and src>>8 | convw x3 | graph bounds ----
__global__ __launch_bounds__(256) void k1_hist(const int* __restrict__ src,
        const int* __restrict__ dst, int* __restrict__ cntD, int* __restrict__ cntS,
        const float* __restrict__ W1, const float* __restrict__ W2, const float* __restrict__ W3,
        unsigned short* __restrict__ W1T, unsigned short* __restrict__ W2T,
        unsigned short* __restrict__ W3T,
        const int* __restrict__ gid, int* __restrict__ gstart) {
    int bid = blockIdx.x, tid = threadIdx.x;
    if (bid < NB_EDGE) {
        __shared__ int hD[256], hS[256];
        hD[tid] = 0; hS[tid] = 0;
        __syncthreads();
        int base = bid * K1_ITEMS;
#pragma unroll
        for (int it = 0; it < 8; it++) {
            int e = base + it * 256 + tid;
            if (e < N_EDGES) {
                atomicAdd(&hD[dst[e] >> 8], 1);
                atomicAdd(&hS[src[e] >> 8], 1);
            }
        }
        __syncthreads();
        cntD[bid * 256 + tid] = hD[tid];
        cntS[bid * 256 + tid] = hS[tid];
        return;
    }
    bid -= NB_EDGE;
    if (bid < CW1_BLOCKS) { convw_body(W1, W1T, IN_DIM, HID, bid * 256 + tid); return; }
    bid -= CW1_BLOCKS;
    if (bid < CW2_BLOCKS) { convw_body(W2, W2T, HID, H2, bid * 256 + tid); return; }
    bid -= CW2_BLOCKS;
    if (bid < CW3_BLOCKS) { convw_body(W3, W3T, H2, H2, bid * 256 + tid); return; }
    bid -= CW3_BLOCKS;
    {   // graph segment starts (graph_ids sorted)
        int n = bid * 256 + tid;
        if (n >= N_NODES) return;
        int g = gid[n];
        int gp = (n == 0) ? -1 : gid[n - 1];
        for (int k = gp + 1; k <= g; k++) gstart[k] = n;
        if (n == N_NODES - 1)
            for (int k = g + 1; k <= N_GRAPHS; k++) gstart[k] = N_NODES;
    }
}

// ---- K2: scan count tables -> per-(block,bucket) offsets + bucket bases ----
__global__ __launch_bounds__(256) void k2_scan(const int* __restrict__ cntD,
        const int* __restrict__ cntS, int* __restrict__ offD, int* __restrict__ offS,
        int* __restrict__ baseD, int* __restrict__ baseS, int* __restrict__ rowptr) {
    int b = threadIdx.x;
    int runD = 0, runS = 0;
    for (int blk = 0; blk < NB_EDGE; blk++) {
        int cD = cntD[blk * 256 + b]; offD[blk * 256 + b] = runD; runD += cD;
        int cS = cntS[blk * 256 + b]; offS[blk * 256 + b] = runS; runS += cS;
    }
    __shared__ int ldsD[256], ldsS[256];
    ldsD[b] = runD; ldsS[b] = runS;
    __syncthreads();
    for (int off = 1; off < 256; off <<= 1) {
        int uD = (b >= off) ? ldsD[b - off] : 0;
        int uS = (b >= off) ? ldsS[b - off] : 0;
        __syncthreads();
        ldsD[b] += uD; ldsS[b] += uS;
        __syncthreads();
    }
    baseD[b] = ldsD[b] - runD;
    baseS[b] = ldsS[b] - runS;
    if (b == 0) rowptr[N_NODES] = N_EDGES;
}

// ---- K3: scatter edges into dst-buckets (uint2{dst,src}) and src-buckets (src) ----
__global__ __launch_bounds__(256) void k3_scatter(const int* __restrict__ src,
        const int* __restrict__ dst, const int* __restrict__ offD, const int* __restrict__ offS,
        const int* __restrict__ baseD, const int* __restrict__ baseS,
        uint2* __restrict__ bufD, int* __restrict__ bufS) {
    __shared__ int cD[256], cS[256];
    int bid = blockIdx.x, tid = threadIdx.x;
    cD[tid] = baseD[tid] + offD[bid * 256 + tid];
    cS[tid] = baseS[tid] + offS[bid * 256 + tid];
    __syncthreads();
    int base = bid * K1_ITEMS;
#pragma unroll
    for (int it = 0; it < 8; it++) {
        int e = base + it * 256 + tid;
        if (e < N_EDGES) {
            int d = dst[e], s = src[e];
            int pd = atomicAdd(&cD[d >> 8], 1);
            bufD[pd] = make_uint2((unsigned)d, (unsigned)s);
            int ps = atomicAdd(&cS[s >> 8], 1);
            bufS[ps] = s;
        }
    }
}

// ---- K45: fused per-bucket CSR build (dst) | outdeg + n_feat prescale (src) ----
__global__ __launch_bounds__(256) void k45_csr_prescale(const uint2* __restrict__ bufD,
        const int* __restrict__ baseD, int* __restrict__ indeg,
        int* __restrict__ rowptr, int* __restrict__ csr_src,
        const int* __restrict__ bufS, const int* __restrict__ baseS,
        const float* __restrict__ n_feat, int* __restrict__ outdeg,
        unsigned int* __restrict__ Xs) {
    int bid = blockIdx.x, t = threadIdx.x;
    if (bid < NBUCK) {
        // per dst-bucket: indeg, rowptr, csr_src (contiguous streams, LDS only)
        __shared__ int cnt[256], lds[256], curs[256];
        int b = bid;
        int eb = baseD[b], ee = baseD[b + 1];
        cnt[t] = 0;
        __syncthreads();
        for (int e = eb + t; e < ee; e += 256)
            atomicAdd(&cnt[bufD[e].x & 255], 1);
        __syncthreads();
        int v = cnt[t];
        lds[t] = v;
        __syncthreads();
        for (int off = 1; off < 256; off <<= 1) {
            int u = (t >= off) ? lds[t - off] : 0;
            __syncthreads();
            lds[t] += u;
            __syncthreads();
        }
        int n0 = b << 8;
        int ex = eb + lds[t] - v;
        if (n0 + t < N_NODES) {
            indeg[n0 + t] = v;
            rowptr[n0 + t] = ex;
        }
        curs[t] = ex;
        __syncthreads();
        for (int e = eb + t; e < ee; e += 256) {
            uint2 ed = bufD[e];
            int slot = atomicAdd(&curs[ed.x & 255], 1);
            csr_src[slot] = (int)ed.y;
        }
        return;
    }
    {   // per src-bucket: outdeg histogram + fused n_feat prescale -> Xs bf16
        __shared__ int cnt[256];
        __shared__ float od[256];
        int b = bid - NBUCK;
        int eb = baseS[b], ee = baseS[b + 1];
        cnt[t] = 0;
        __syncthreads();
        for (int e = eb + t; e < ee; e += 256)
            atomicAdd(&cnt[bufS[e] & 255], 1);
        __syncthreads();
        int n0 = b << 8;
        int nn = min(256, N_NODES - n0);
        if (t < nn) outdeg[n0 + t] = cnt[t];
        od[t] = rsqrtf(fmaxf((float)cnt[t], 1.0f));
        __syncthreads();
        int pc = t & 127;       // pair-column
        int rh = t >> 7;        // row parity
        for (int r = rh; r < nn; r += 2) {
            int row = n0 + r;
            float2 v = *reinterpret_cast<const float2*>(n_feat + (size_t)row * 128 + pc * 2);
            float s = od[r];
            Xs[(size_t)row * 64 + pc] = pack2(v.x * s, v.y * s);
        }
    }
}

// ---- pull aggregation: wave/node, uint4/lane (16 lanes = full 256B row) ----
// 4 edges per gather instruction; main loop 16 edges with 4 gathers in flight
// (8KB outstanding/wave). Indices via wave-uniform scalar loads + 3 cndmask
// selects. Tail: one predicated batch. Reduce: shfl_xor 16,32 across groups.
// MODE 0: out = bf16(acc * id)
// MODE 1: out = bf16(relu(acc*id + bias) * od)   (pre-scales for next layer)
template<int MODE>
__global__ __launch_bounds__(256) void pull_agg(const uint4* __restrict__ X,
        const int* __restrict__ rowptr, const int* __restrict__ csr_src,
        const int* __restrict__ indeg, const int* __restrict__ outdeg,
        const float* __restrict__ bias, uint4* __restrict__ out) {
    int lane = threadIdx.x & 63;
    int n = blockIdx.x * 4 + (threadIdx.x >> 6);
    n = __builtin_amdgcn_readfirstlane(n);     // wave-uniform -> scalar loads
    if (n >= N_NODES) return;
    int grp = lane >> 4;       // which of 4 edges in a 4-edge unit
    int l16 = lane & 15;       // 16B chunk within the 256B row
    int beg = rowptr[n];
    int cnt = rowptr[n + 1] - beg;
    const int* ep = csr_src + beg;
    float a[8];
#pragma unroll
    for (int k = 0; k < 8; k++) a[k] = 0.f;

    auto accum = [&](uint4 u) {
        a[0] += bf2f((unsigned short)(u.x & 0xffff));
        a[1] += bf2f((unsigned short)(u.x >> 16));
        a[2] += bf2f((unsigned short)(u.y & 0xffff));
        a[3] += bf2f((unsigned short)(u.y >> 16));
        a[4] += bf2f((unsigned short)(u.z & 0xffff));
        a[5] += bf2f((unsigned short)(u.z >> 16));
        a[6] += bf2f((unsigned short)(u.w & 0xffff));
        a[7] += bf2f((unsigned short)(u.w >> 16));
    };
    auto sel4 = [&](int s0, int s1, int s2, int s3) {
        int s = (grp == 0) ? s0 : (grp == 1) ? s1 : (grp == 2) ? s2 : s3;
        return s;
    };

    int j = 0;
    for (; j + 16 <= cnt; j += 16) {
        uint4 u[4];
#pragma unroll
        for (int q = 0; q < 4; q++) {
            int s = sel4(ep[j + 4 * q], ep[j + 4 * q + 1],
                         ep[j + 4 * q + 2], ep[j + 4 * q + 3]);
            u[q] = X[((size_t)s << 4) + l16];
        }
#pragma unroll
        for (int q = 0; q < 4; q++) accum(u[q]);
    }
    if (j < cnt) {   // single predicated batch covers the whole tail (<=15 edges)
        int last = cnt - 1;
        uint4 u[4];
#pragma unroll
        for (int q = 0; q < 4; q++) {
            int jb = j + 4 * q;
            int s = sel4(ep[min(jb, last)], ep[min(jb + 1, last)],
                         ep[min(jb + 2, last)], ep[min(jb + 3, last)]);
            uint4 v = X[((size_t)s << 4) + l16];
            bool ok = (jb + grp) < cnt;
            u[q].x = ok ? v.x : 0u;   // bf16 0x0000 == 0.0f
            u[q].y = ok ? v.y : 0u;
            u[q].z = ok ? v.z : 0u;
            u[q].w = ok ? v.w : 0u;
        }
#pragma unroll
        for (int q = 0; q < 4; q++) accum(u[q]);
    }

    // fold the 4 edge-groups: pairs (0,1)/(2,3) then halves
#pragma unroll
    for (int k = 0; k < 8; k++) {
        a[k] += __shfl_xor(a[k], 16);
        a[k] += __shfl_xor(a[k], 32);
    }

    if (lane < 16) {
        float id = rsqrtf(fmaxf((float)indeg[n], 1.0f));
#pragma unroll
        for (int k = 0; k < 8; k++) a[k] *= id;
        if (MODE == 1) {
            float odv = rsqrtf(fmaxf((float)outdeg[n], 1.0f));
            float4 b0 = *reinterpret_cast<const float4*>(bias + l16 * 8);
            float4 b1 = *reinterpret_cast<const float4*>(bias + l16 * 8 + 4);
            a[0] = fmaxf(a[0] + b0.x, 0.f) * odv;
            a[1] = fmaxf(a[1] + b0.y, 0.f) * odv;
            a[2] = fmaxf(a[2] + b0.z, 0.f) * odv;
            a[3] = fmaxf(a[3] + b0.w, 0.f) * odv;
            a[4] = fmaxf(a[4] + b1.x, 0.f) * odv;
            a[5] = fmaxf(a[5] + b1.y, 0.f) * odv;
            a[6] = fmaxf(a[6] + b1.z, 0.f) * odv;
            a[7] = fmaxf(a[7] + b1.w, 0.f) * odv;
        }
        uint4 o;
        o.x = pack2(a[0], a[1]);
        o.y = pack2(a[2], a[3]);
        o.z = pack2(a[4], a[5]);
        o.w = pack2(a[6], a[7]);
        out[((size_t)n << 4) + l16] = o;
    }
}

// ---------------- MFMA bf16 GEMM, B-resident-in-registers, A streamed ----------------
// out[M,NOUT] = A[M,K] @ W[K,NOUT].  WT: bf16 [NOUT][K] (= W^T).
// EPI 1: bias+relu (aux=bias[NOUT])   EPI 2: row-scale by rsqrt(outdeg) (auxi=outdeg)
// F32OUT: write float (numeric headroom for the pooled layer).
template<int K, int NOUT, int EPI, bool F32OUT>
__global__ __launch_bounds__(256) void mfma_gemm(const unsigned short* __restrict__ A,
        const unsigned short* __restrict__ WT, const float* __restrict__ aux,
        const int* __restrict__ auxi, void* __restrict__ outv) {
    constexpr int KK  = K / 32;      // MFMA k-steps
    constexpr int NBW = NOUT / 64;   // 16-col blocks per wave (4 or 2)
    int wave = threadIdx.x >> 6;
    int lane = threadIdx.x & 63;
    int col0 = lane & 15;
    int kgrp = (lane >> 4) * 8;
    int wcol = wave * NBW * 16;

    short8_t b[NBW][KK];
    {
        const unsigned short* wbase = WT + (size_t)(wcol + col0) * K + kgrp;
#pragma unroll
        for (int n = 0; n < NBW; n++)
#pragma unroll
            for (int kk = 0; kk < KK; kk++)
                b[n][kk] = *reinterpret_cast<const short8_t*>(
                    wbase + (size_t)n * 16 * K + kk * 32);
    }
    float bv[NBW];
    if (EPI == 1) {
#pragma unroll
        for (int n = 0; n < NBW; n++) bv[n] = aux[wcol + n * 16 + col0];
    }

    constexpr int NT = N_NODES / 16;   // 3125 row tiles, exact
    for (int rt = blockIdx.x; rt < NT; rt += gridDim.x) {
        const unsigned short* ap = A + (size_t)(rt * 16 + col0) * K + kgrp;
        short8_t a[KK];
#pragma unroll
        for (int kk = 0; kk < KK; kk++)
            a[kk] = *reinterpret_cast<const short8_t*>(ap + kk * 32);

        f32x4 acc[NBW];
#pragma unroll
        for (int n = 0; n < NBW; n++) acc[n] = f32x4{0.f, 0.f, 0.f, 0.f};
#pragma unroll
        for (int kk = 0; kk < KK; kk++)
#pragma unroll
            for (int n = 0; n < NBW; n++)
                acc[n] = __builtin_amdgcn_mfma_f32_16x16x32_bf16(a[kk], b[n][kk], acc[n], 0, 0, 0);

        // C/D layout: col = lane&15, row = (lane>>4)*4 + reg
        int rbase = rt * 16 + ((lane >> 4) << 2);
        float rs[4];
        if (EPI == 2) {
#pragma unroll
            for (int j = 0; j < 4; j++)
                rs[j] = rsqrtf(fmaxf((float)auxi[rbase + j], 1.0f));
        }
#pragma unroll
        for (int n = 0; n < NBW; n++) {
            int col = wcol + n * 16 + col0;
#pragma unroll
            for (int j = 0; j < 4; j++) {
                float v = acc[n][j];
                if (EPI == 1) v = fmaxf(v + bv[n], 0.f);
                if (EPI == 2) v = v * rs[j];
                if (F32OUT)
                    ((float*)outv)[(size_t)(rbase + j) * NOUT + col] = v;
                else
                    ((unsigned short*)outv)[(size_t)(rbase + j) * NOUT + col] = f2bf(v);
            }
        }
    }
}

// ---------------- sum pooling over contiguous segments (f32 in, f32 out) ----------
__global__ __launch_bounds__(512) void seg_pool(const float* __restrict__ X,
        const int* __restrict__ gstart, float* __restrict__ emb) {
    int g = blockIdx.x;
    int lane = threadIdx.x & 63;      // 2 cols per lane
    int stripe = threadIdx.x >> 6;    // 0..7
    int beg = gstart[g], end = gstart[g + 1];
    float ax = 0.f, ay = 0.f;
    for (int r = beg + stripe; r < end; r += 8) {
        float2 v = *reinterpret_cast<const float2*>(X + (size_t)r * 128 + lane * 2);
        ax += v.x; ay += v.y;
    }
    __shared__ float bufx[8][64], bufy[8][64];
    bufx[stripe][lane] = ax;
    bufy[stripe][lane] = ay;
    __syncthreads();
    if (stripe == 0) {
        float sx = 0.f, sy = 0.f;
#pragma unroll
        for (int q = 0; q < 8; q++) { sx += bufx[q][lane]; sy += bufy[q][lane]; }
        emb[g * 128 + lane * 2]     = sx;
        emb[g * 128 + lane * 2 + 1] = sy;
    }
}

// ---------------- fused BN + FC head + log_softmax ----------------
__global__ __launch_bounds__(128) void fc_kernel(const float* __restrict__ emb,
        const float* __restrict__ gamma, const float* __restrict__ beta,
        const float* __restrict__ Wf1, const float* __restrict__ bf1,
        const float* __restrict__ Wf2, const float* __restrict__ bf2,
        float* __restrict__ out_ls) {
    __shared__ float h[H2];
    __shared__ float logits[OUT_DIM];
    int g = blockIdx.x;
    int j = threadIdx.x;
    float s = 0.f;
    for (int q = 0; q < N_GRAPHS; q++) s += emb[q * 128 + j];
    float mean = s * (1.0f / N_GRAPHS);
    float v = 0.f;
    for (int q = 0; q < N_GRAPHS; q++) {
        float d = emb[q * 128 + j] - mean;
        v += d * d;
    }
    v *= (1.0f / N_GRAPHS);
    float scale = rsqrtf(v + BN_EPS) * gamma[j];
    h[j] = (emb[g * 128 + j] - mean) * scale + beta[j];
    __syncthreads();
    float acc = bf1[j];
    for (int k = 0; k < H2; k++) acc += h[k] * Wf1[k * H2 + j];
    __syncthreads();
    h[j] = fmaxf(acc, 0.f);
    __syncthreads();
    if (j < OUT_DIM) {
        float a2 = bf2[j];
        for (int k = 0; k < H2; k++) a2 += h[k] * Wf2[k * OUT_DIM + j];
        logits[j] = a2;
    }
    __syncthreads();
    if (j < OUT_DIM) {
        float m = -1e30f;
        for (int o = 0; o < OUT_DIM; o++) m = fmaxf(m, logits[o]);
        float se = 0.f;
        for (int o = 0; o < OUT_DIM; o++) se += expf(logits[o] - m);
        out_ls[g * OUT_DIM + j] = logits[j] - m - logf(se);
    }
}

extern "C" void kernel_launch(void* const* d_in, const int* in_sizes, int n_in,
                              void* d_out, int out_size, void* d_ws, size_t ws_size,
                              hipStream_t stream) {
    const float* n_feat = (const float*)d_in[0];
    const int*   src    = (const int*)d_in[1];
    const int*   dst    = (const int*)d_in[2];
    const int*   gid    = (const int*)d_in[3];
    const float* W1     = (const float*)d_in[4];
    const float* b1     = (const float*)d_in[5];
    const float* W2     = (const float*)d_in[6];
    const float* b2     = (const float*)d_in[7];
    const float* W3     = (const float*)d_in[8];
    const float* b3     = (const float*)d_in[9];
    const float* Wf1    = (const float*)d_in[10];
    const float* bf1    = (const float*)d_in[11];
    const float* Wf2    = (const float*)d_in[12];
    const float* bf2    = (const float*)d_in[13];
    const float* gamma  = (const float*)d_in[14];
    const float* beta   = (const float*)d_in[15];
    float* out = (float*)d_out;

    char* ws = (char*)d_ws;
    size_t off = 0;
    auto alloc = [&](size_t bytes) {
        void* p = ws + off;
        off = (off + bytes + 255) & ~(size_t)255;
        return p;
    };
    int* cntD    = (int*)alloc((size_t)NB_EDGE * 256 * 4);
    int* cntS    = (int*)alloc((size_t)NB_EDGE * 256 * 4);
    int* offD    = (int*)alloc((size_t)NB_EDGE * 256 * 4);
    int* offS    = (int*)alloc((size_t)NB_EDGE * 256 * 4);
    int* baseD   = (int*)alloc(257 * 4);
    int* baseS   = (int*)alloc(257 * 4);
    int* indeg   = (int*)alloc((size_t)N_NODES * 4);
    int* outdeg  = (int*)alloc((size_t)N_NODES * 4);
    int* rowptr  = (int*)alloc((size_t)(N_NODES + 1) * 4);
    int* gstart  = (int*)alloc((size_t)(N_GRAPHS + 1) * 4);
    uint2* bufD  = (uint2*)alloc((size_t)N_EDGES * 8);
    int* bufS    = (int*)alloc((size_t)N_EDGES * 4);
    int* csr_src = (int*)alloc((size_t)N_EDGES * 4);
    unsigned short* Xs  = (unsigned short*)alloc((size_t)N_NODES * 128 * 2);
    unsigned short* A   = (unsigned short*)alloc((size_t)N_NODES * 128 * 2);
    unsigned short* B   = (unsigned short*)alloc((size_t)N_NODES * 256 * 2);  // also f32 [N,128]
    unsigned short* W1T = (unsigned short*)alloc((size_t)IN_DIM * HID * 2);
    unsigned short* W2T = (unsigned short*)alloc((size_t)HID * H2 * 2);
    unsigned short* W3T = (unsigned short*)alloc((size_t)H2 * H2 * 2);
    float* Bf32 = (float*)B;   // N*256*2 bytes == N*128*4 bytes

    // preprocessing: zero global atomics
    k1_hist<<<NB_EDGE + CW1_BLOCKS + CW2_BLOCKS + CW3_BLOCKS + BND_BLOCKS, 256, 0, stream>>>(
        src, dst, cntD, cntS, W1, W2, W3, W1T, W2T, W3T, gid, gstart);
    k2_scan<<<1, 256, 0, stream>>>(cntD, cntS, offD, offS, baseD, baseS, rowptr);
    k3_scatter<<<NB_EDGE, 256, 0, stream>>>(src, dst, offD, offS, baseD, baseS, bufD, bufS);
    k45_csr_prescale<<<NBUCK * 2, 256, 0, stream>>>(bufD, baseD, indeg, rowptr, csr_src,
                                                    bufS, baseS, n_feat, outdeg,
                                                    (unsigned int*)Xs);

    const int AGG_GRID = (N_NODES + 3) / 4;
    const int GEMM_GRID = 1024;

    // Layer 1: A = bf16(agg(Xs)·id); B = bf16(relu(A@W1 + b1))  [N,256]
    pull_agg<0><<<AGG_GRID, 256, 0, stream>>>((const uint4*)Xs, rowptr, csr_src,
                                              indeg, outdeg, nullptr, (uint4*)A);
    mfma_gemm<128, 256, 1, false><<<GEMM_GRID, 256, 0, stream>>>(A, W1T, b1, nullptr, B);

    // Layer 2: A = bf16((X1@W2)·od); B = bf16(relu(agg(A)·id + b2)·od)
    mfma_gemm<256, 128, 2, false><<<GEMM_GRID, 256, 0, stream>>>(B, W2T, nullptr, outdeg, A);
    pull_agg<1><<<AGG_GRID, 256, 0, stream>>>((const uint4*)A, rowptr, csr_src,
                                              indeg, outdeg, b2, (uint4*)B);

    // Layer 3: A = bf16(agg(B)·id); Bf32 = relu(A@W3 + b3)  [f32 for pooling accuracy]
    pull_agg<0><<<AGG_GRID, 256, 0, stream>>>((const uint4*)B, rowptr, csr_src,
                                              indeg, outdeg, nullptr, (uint4*)A);
    mfma_gemm<128, 128, 1, true><<<GEMM_GRID, 256, 0, stream>>>(A, W3T, b3, nullptr, Bf32);

    // Readout
    seg_pool<<<N_GRAPHS, 512, 0, stream>>>(Bf32, gstart, out);
    fc_kernel<<<N_GRAPHS, 128, 0, stream>>>(out, gamma, beta, Wf1, bf1, Wf2, bf2,
                                            out + (size_t)N_GRAPHS * H2);
}

// Round 14
// 249.961 us; speedup vs baseline: 7.0819x; 1.0219x over previous
//
#include <hip/hip_runtime.h>

#define N_NODES 50000
#define N_EDGES 800000
#define N_GRAPHS 128
#define IN_DIM 128
#define HID 256
#define H2 128
#define OUT_DIM 10
#define BN_EPS 1e-5f

#define NBUCK 196                              // dst>>8 buckets (50000/256)
#define K1_ITEMS 2048
#define NB_EDGE ((N_EDGES + K1_ITEMS - 1) / K1_ITEMS)   // 391
#define BND_BLOCKS ((N_NODES + 255) / 256)     // 196
#define CW1_BLOCKS  ((IN_DIM * HID) / 256)     // 128
#define CW2_BLOCKS  ((HID * H2) / 256)         // 128
#define CW3_BLOCKS  ((H2 * H2) / 256)          // 64

typedef __attribute__((ext_vector_type(8))) short short8_t;   // 8 bf16 (4 VGPRs)
typedef __attribute__((ext_vector_type(4))) float f32x4;

__device__ __forceinline__ unsigned short f2bf(float f) {
    union { float f; unsigned u; } x; x.f = f;
    unsigned r = x.u + 0x7fffu + ((x.u >> 16) & 1u);   // round-to-nearest-even
    return (unsigned short)(r >> 16);
}
__device__ __forceinline__ float bf2f(unsigned short h) {
    union { unsigned u; float f; } x; x.u = ((unsigned)h) << 16;
    return x.f;
}
__device__ __forceinline__ unsigned pack2(float a, float b) {
    return (unsigned)f2bf(a) | ((unsigned)f2bf(b) << 16);
}

__device__ __forceinline__ void convw_body(const float* __restrict__ W,
        unsigned short* __restrict__ WT, int K, int NOUT, int i) {
    int k = i / NOUT, n = i - k * NOUT;
    WT[(size_t)n * K + k] = f2bf(W[i]);
}

// ---- K1: per-block LDS histograms of dst>>8 and src>>8 | convw x3 | graph bounds ----
__global__ __launch_bounds__(256) void k1_hist(const int* __restrict__ src,
        const int* __restrict__ dst, int* __restrict__ cntD, int* __restrict__ cntS,
        const float* __restrict__ W1, const float* __restrict__ W2, const float* __restrict__ W3,
        unsigned short* __restrict__ W1T, unsigned short* __restrict__ W2T,
        unsigned short* __restrict__ W3T,
        const int* __restrict__ gid, int* __restrict__ gstart) {
    int bid = blockIdx.x, tid = threadIdx.x;
    if (bid < NB_EDGE) {
        __shared__ int hD[256], hS[256];
        hD[tid] = 0; hS[tid] = 0;
        __syncthreads();
        int base = bid * K1_ITEMS;
#pragma unroll
        for (int it = 0; it < 8; it++) {
            int e = base + it * 256 + tid;
            if (e < N_EDGES) {
                atomicAdd(&hD[dst[e] >> 8], 1);
                atomicAdd(&hS[src[e] >> 8], 1);
            }
        }
        __syncthreads();
        cntD[bid * 256 + tid] = hD[tid];
        cntS[bid * 256 + tid] = hS[tid];
        return;
    }
    bid -= NB_EDGE;
    if (bid < CW1_BLOCKS) { convw_body(W1, W1T, IN_DIM, HID, bid * 256 + tid); return; }
    bid -= CW1_BLOCKS;
    if (bid < CW2_BLOCKS) { convw_body(W2, W2T, HID, H2, bid * 256 + tid); return; }
    bid -= CW2_BLOCKS;
    if (bid < CW3_BLOCKS) { convw_body(W3, W3T, H2, H2, bid * 256 + tid); return; }
    bid -= CW3_BLOCKS;
    {   // graph segment starts (graph_ids sorted)
        int n = bid * 256 + tid;
        if (n >= N_NODES) return;
        int g = gid[n];
        int gp = (n == 0) ? -1 : gid[n - 1];
        for (int k = gp + 1; k <= g; k++) gstart[k] = n;
        if (n == N_NODES - 1)
            for (int k = g + 1; k <= N_GRAPHS; k++) gstart[k] = N_NODES;
    }
}

// ---- K2: scan count tables -> per-(block,bucket) offsets + bucket bases ----
__global__ __launch_bounds__(256) void k2_scan(const int* __restrict__ cntD,
        const int* __restrict__ cntS, int* __restrict__ offD, int* __restrict__ offS,
        int* __restrict__ baseD, int* __restrict__ baseS, int* __restrict__ rowptr) {
    int b = threadIdx.x;
    int runD = 0, runS = 0;
    for (int blk = 0; blk < NB_EDGE; blk++) {
        int cD = cntD[blk * 256 + b]; offD[blk * 256 + b] = runD; runD += cD;
        int cS = cntS[blk * 256 + b]; offS[blk * 256 + b] = runS; runS += cS;
    }
    __shared__ int ldsD[256], ldsS[256];
    ldsD[b] = runD; ldsS[b] = runS;
    __syncthreads();
    for (int off = 1; off < 256; off <<= 1) {
        int uD = (b >= off) ? ldsD[b - off] : 0;
        int uS = (b >= off) ? ldsS[b - off] : 0;
        __syncthreads();
        ldsD[b] += uD; ldsS[b] += uS;
        __syncthreads();
    }
    baseD[b] = ldsD[b] - runD;
    baseS[b] = ldsS[b] - runS;
    if (b == 0) rowptr[N_NODES] = N_EDGES;
}

// ---- K3: scatter edges into dst-buckets (uint2{dst,src}) and src-buckets (src) ----
__global__ __launch_bounds__(256) void k3_scatter(const int* __restrict__ src,
        const int* __restrict__ dst, const int* __restrict__ offD, const int* __restrict__ offS,
        const int* __restrict__ baseD, const int* __restrict__ baseS,
        uint2* __restrict__ bufD, int* __restrict__ bufS) {
    __shared__ int cD[256], cS[256];
    int bid = blockIdx.x, tid = threadIdx.x;
    cD[tid] = baseD[tid] + offD[bid * 256 + tid];
    cS[tid] = baseS[tid] + offS[bid * 256 + tid];
    __syncthreads();
    int base = bid * K1_ITEMS;
#pragma unroll
    for (int it = 0; it < 8; it++) {
        int e = base + it * 256 + tid;
        if (e < N_EDGES) {
            int d = dst[e], s = src[e];
            int pd = atomicAdd(&cD[d >> 8], 1);
            bufD[pd] = make_uint2((unsigned)d, (unsigned)s);
            int ps = atomicAdd(&cS[s >> 8], 1);
            bufS[ps] = s;
        }
    }
}

// ---- K45: fused per-bucket CSR build (dst) | outdeg + n_feat prescale (src) ----
__global__ __launch_bounds__(256) void k45_csr_prescale(const uint2* __restrict__ bufD,
        const int* __restrict__ baseD, int* __restrict__ indeg,
        int* __restrict__ rowptr, int* __restrict__ csr_src,
        const int* __restrict__ bufS, const int* __restrict__ baseS,
        const float* __restrict__ n_feat, int* __restrict__ outdeg,
        unsigned int* __restrict__ Xs) {
    int bid = blockIdx.x, t = threadIdx.x;
    if (bid < NBUCK) {
        // per dst-bucket: indeg, rowptr, csr_src (contiguous streams, LDS only)
        __shared__ int cnt[256], lds[256], curs[256];
        int b = bid;
        int eb = baseD[b], ee = baseD[b + 1];
        cnt[t] = 0;
        __syncthreads();
        for (int e = eb + t; e < ee; e += 256)
            atomicAdd(&cnt[bufD[e].x & 255], 1);
        __syncthreads();
        int v = cnt[t];
        lds[t] = v;
        __syncthreads();
        for (int off = 1; off < 256; off <<= 1) {
            int u = (t >= off) ? lds[t - off] : 0;
            __syncthreads();
            lds[t] += u;
            __syncthreads();
        }
        int n0 = b << 8;
        int ex = eb + lds[t] - v;
        if (n0 + t < N_NODES) {
            indeg[n0 + t] = v;
            rowptr[n0 + t] = ex;
        }
        curs[t] = ex;
        __syncthreads();
        for (int e = eb + t; e < ee; e += 256) {
            uint2 ed = bufD[e];
            int slot = atomicAdd(&curs[ed.x & 255], 1);
            csr_src[slot] = (int)ed.y;
        }
        return;
    }
    {   // per src-bucket: outdeg histogram + fused n_feat prescale -> Xs bf16
        __shared__ int cnt[256];
        __shared__ float od[256];
        int b = bid - NBUCK;
        int eb = baseS[b], ee = baseS[b + 1];
        cnt[t] = 0;
        __syncthreads();
        for (int e = eb + t; e < ee; e += 256)
            atomicAdd(&cnt[bufS[e] & 255], 1);
        __syncthreads();
        int n0 = b << 8;
        int nn = min(256, N_NODES - n0);
        if (t < nn) outdeg[n0 + t] = cnt[t];
        od[t] = rsqrtf(fmaxf((float)cnt[t], 1.0f));
        __syncthreads();
        int pc = t & 127;       // pair-column
        int rh = t >> 7;        // row parity
        for (int r = rh; r < nn; r += 2) {
            int row = n0 + r;
            float2 v = *reinterpret_cast<const float2*>(n_feat + (size_t)row * 128 + pc * 2);
            float s = od[r];
            Xs[(size_t)row * 64 + pc] = pack2(v.x * s, v.y * s);
        }
    }
}

// ---- pull aggregation: wave/node, paired rows, 8B/lane, scalar indices ----
// Software-pipelined: gathers for batch j issued, then batch j+1's indices
// scalar-loaded while gathers are in flight, then batch j accumulated
// (predicated if partial). One code path; cnt=0 guarded.
// MODE 0: out = bf16(acc * id)
// MODE 1: out = bf16(relu(acc*id + bias) * od)   (pre-scales for next layer)
template<int MODE>
__global__ __launch_bounds__(256) void pull_agg(const unsigned int* __restrict__ X,
        const int* __restrict__ rowptr, const int* __restrict__ csr_src,
        const int* __restrict__ indeg, const int* __restrict__ outdeg,
        const float* __restrict__ bias, unsigned int* __restrict__ out) {
    int lane = threadIdx.x & 63;
    int n = blockIdx.x * 4 + (threadIdx.x >> 6);
    n = __builtin_amdgcn_readfirstlane(n);     // wave-uniform -> scalar loads
    if (n >= N_NODES) return;
    int l32 = lane & 31;
    int half = lane >> 5;
    int beg = rowptr[n];
    int cnt = rowptr[n + 1] - beg;
    const int* ep = csr_src + beg;
    float a0 = 0.f, a1 = 0.f, a2 = 0.f, a3 = 0.f;
    int voff = l32 << 1;

    if (cnt > 0) {
        int last = cnt - 1;
        int idx[8];
        // prefetch batch 0 indices (clamped scalar loads)
#pragma unroll
        for (int q = 0; q < 8; q++) {
            int ja = 2 * q, jb = ja + 1;
            int sa = ep[min(ja, last)], sb = ep[min(jb, last)];
            idx[q] = half ? sb : sa;
        }
        int j = 0;
        while (true) {
            // issue 8 gathers for the current batch
            uint2 u[8];
#pragma unroll
            for (int q = 0; q < 8; q++)
                u[q] = *reinterpret_cast<const uint2*>(X + ((size_t)idx[q] << 6) + voff);

            int jn = j + 16;
            bool more = jn < cnt;
            // prefetch next batch's indices while gathers are in flight
            if (more) {
#pragma unroll
                for (int q = 0; q < 8; q++) {
                    int ja = jn + 2 * q, jb = ja + 1;
                    int sa = ep[min(ja, last)], sb = ep[min(jb, last)];
                    idx[q] = half ? sb : sa;
                }
            }
            // accumulate current batch
            if (j + 16 <= cnt) {
#pragma unroll
                for (int q = 0; q < 8; q++) {
                    a0 += bf2f((unsigned short)(u[q].x & 0xffff));
                    a1 += bf2f((unsigned short)(u[q].x >> 16));
                    a2 += bf2f((unsigned short)(u[q].y & 0xffff));
                    a3 += bf2f((unsigned short)(u[q].y >> 16));
                }
            } else {   // partial batch: cndmask-zero invalid edge slots
#pragma unroll
                for (int q = 0; q < 8; q++) {
                    int jj = j + 2 * q + half;
                    bool ok = jj < cnt;
                    unsigned vx = ok ? u[q].x : 0u;   // bf16 0x0000 == 0.0f
                    unsigned vy = ok ? u[q].y : 0u;
                    a0 += bf2f((unsigned short)(vx & 0xffff));
                    a1 += bf2f((unsigned short)(vx >> 16));
                    a2 += bf2f((unsigned short)(vy & 0xffff));
                    a3 += bf2f((unsigned short)(vy >> 16));
                }
            }
            if (!more) break;
            j = jn;
        }
    }

    a0 += __shfl_xor(a0, 32);
    a1 += __shfl_xor(a1, 32);
    a2 += __shfl_xor(a2, 32);
    a3 += __shfl_xor(a3, 32);

    if (lane < 32) {
        float id = rsqrtf(fmaxf((float)indeg[n], 1.0f));
        float v0 = a0 * id, v1 = a1 * id, v2 = a2 * id, v3 = a3 * id;
        if (MODE == 1) {
            float odv = rsqrtf(fmaxf((float)outdeg[n], 1.0f));
            float4 bv = *reinterpret_cast<const float4*>(bias + l32 * 4);
            v0 = fmaxf(v0 + bv.x, 0.f) * odv;
            v1 = fmaxf(v1 + bv.y, 0.f) * odv;
            v2 = fmaxf(v2 + bv.z, 0.f) * odv;
            v3 = fmaxf(v3 + bv.w, 0.f) * odv;
        }
        uint2 o = make_uint2(pack2(v0, v1), pack2(v2, v3));
        *reinterpret_cast<uint2*>(out + (size_t)n * 64 + voff) = o;
    }
}

// ---------------- MFMA bf16 GEMM, B-resident-in-registers, A streamed ----------------
// out[M,NOUT] = A[M,K] @ W[K,NOUT].  WT: bf16 [NOUT][K] (= W^T).
// EPI 1: bias+relu (aux=bias[NOUT])   EPI 2: row-scale by rsqrt(outdeg) (auxi=outdeg)
// F32OUT: write float (numeric headroom for the pooled layer).
template<int K, int NOUT, int EPI, bool F32OUT>
__global__ __launch_bounds__(256) void mfma_gemm(const unsigned short* __restrict__ A,
        const unsigned short* __restrict__ WT, const float* __restrict__ aux,
        const int* __restrict__ auxi, void* __restrict__ outv) {
    constexpr int KK  = K / 32;      // MFMA k-steps
    constexpr int NBW = NOUT / 64;   // 16-col blocks per wave (4 or 2)
    int wave = threadIdx.x >> 6;
    int lane = threadIdx.x & 63;
    int col0 = lane & 15;
    int kgrp = (lane >> 4) * 8;
    int wcol = wave * NBW * 16;

    short8_t b[NBW][KK];
    {
        const unsigned short* wbase = WT + (size_t)(wcol + col0) * K + kgrp;
#pragma unroll
        for (int n = 0; n < NBW; n++)
#pragma unroll
            for (int kk = 0; kk < KK; kk++)
                b[n][kk] = *reinterpret_cast<const short8_t*>(
                    wbase + (size_t)n * 16 * K + kk * 32);
    }
    float bv[NBW];
    if (EPI == 1) {
#pragma unroll
        for (int n = 0; n < NBW; n++) bv[n] = aux[wcol + n * 16 + col0];
    }

    constexpr int NT = N_NODES / 16;   // 3125 row tiles, exact
    for (int rt = blockIdx.x; rt < NT; rt += gridDim.x) {
        const unsigned short* ap = A + (size_t)(rt * 16 + col0) * K + kgrp;
        short8_t a[KK];
#pragma unroll
        for (int kk = 0; kk < KK; kk++)
            a[kk] = *reinterpret_cast<const short8_t*>(ap + kk * 32);

        f32x4 acc[NBW];
#pragma unroll
        for (int n = 0; n < NBW; n++) acc[n] = f32x4{0.f, 0.f, 0.f, 0.f};
#pragma unroll
        for (int kk = 0; kk < KK; kk++)
#pragma unroll
            for (int n = 0; n < NBW; n++)
                acc[n] = __builtin_amdgcn_mfma_f32_16x16x32_bf16(a[kk], b[n][kk], acc[n], 0, 0, 0);

        // C/D layout: col = lane&15, row = (lane>>4)*4 + reg
        int rbase = rt * 16 + ((lane >> 4) << 2);
        float rs[4];
        if (EPI == 2) {
#pragma unroll
            for (int j = 0; j < 4; j++)
                rs[j] = rsqrtf(fmaxf((float)auxi[rbase + j], 1.0f));
        }
#pragma unroll
        for (int n = 0; n < NBW; n++) {
            int col = wcol + n * 16 + col0;
#pragma unroll
            for (int j = 0; j < 4; j++) {
                float v = acc[n][j];
                if (EPI == 1) v = fmaxf(v + bv[n], 0.f);
                if (EPI == 2) v = v * rs[j];
                if (F32OUT)
                    ((float*)outv)[(size_t)(rbase + j) * NOUT + col] = v;
                else
                    ((unsigned short*)outv)[(size_t)(rbase + j) * NOUT + col] = f2bf(v);
            }
        }
    }
}

// ---------------- sum pooling over contiguous segments (f32 in, f32 out) ----------
__global__ __launch_bounds__(512) void seg_pool(const float* __restrict__ X,
        const int* __restrict__ gstart, float* __restrict__ emb) {
    int g = blockIdx.x;
    int lane = threadIdx.x & 63;      // 2 cols per lane
    int stripe = threadIdx.x >> 6;    // 0..7
    int beg = gstart[g], end = gstart[g + 1];
    float ax = 0.f, ay = 0.f;
    for (int r = beg + stripe; r < end; r += 8) {
        float2 v = *reinterpret_cast<const float2*>(X + (size_t)r * 128 + lane * 2);
        ax += v.x; ay += v.y;
    }
    __shared__ float bufx[8][64], bufy[8][64];
    bufx[stripe][lane] = ax;
    bufy[stripe][lane] = ay;
    __syncthreads();
    if (stripe == 0) {
        float sx = 0.f, sy = 0.f;
#pragma unroll
        for (int q = 0; q < 8; q++) { sx += bufx[q][lane]; sy += bufy[q][lane]; }
        emb[g * 128 + lane * 2]     = sx;
        emb[g * 128 + lane * 2 + 1] = sy;
    }
}

// ---------------- fused BN + FC head + log_softmax ----------------
__global__ __launch_bounds__(128) void fc_kernel(const float* __restrict__ emb,
        const float* __restrict__ gamma, const float* __restrict__ beta,
        const float* __restrict__ Wf1, const float* __restrict__ bf1,
        const float* __restrict__ Wf2, const float* __restrict__ bf2,
        float* __restrict__ out_ls) {
    __shared__ float h[H2];
    __shared__ float logits[OUT_DIM];
    int g = blockIdx.x;
    int j = threadIdx.x;
    float s = 0.f;
    for (int q = 0; q < N_GRAPHS; q++) s += emb[q * 128 + j];
    float mean = s * (1.0f / N_GRAPHS);
    float v = 0.f;
    for (int q = 0; q < N_GRAPHS; q++) {
        float d = emb[q * 128 + j] - mean;
        v += d * d;
    }
    v *= (1.0f / N_GRAPHS);
    float scale = rsqrtf(v + BN_EPS) * gamma[j];
    h[j] = (emb[g * 128 + j] - mean) * scale + beta[j];
    __syncthreads();
    float acc = bf1[j];
    for (int k = 0; k < H2; k++) acc += h[k] * Wf1[k * H2 + j];
    __syncthreads();
    h[j] = fmaxf(acc, 0.f);
    __syncthreads();
    if (j < OUT_DIM) {
        float a2 = bf2[j];
        for (int k = 0; k < H2; k++) a2 += h[k] * Wf2[k * OUT_DIM + j];
        logits[j] = a2;
    }
    __syncthreads();
    if (j < OUT_DIM) {
        float m = -1e30f;
        for (int o = 0; o < OUT_DIM; o++) m = fmaxf(m, logits[o]);
        float se = 0.f;
        for (int o = 0; o < OUT_DIM; o++) se += expf(logits[o] - m);
        out_ls[g * OUT_DIM + j] = logits[j] - m - logf(se);
    }
}

extern "C" void kernel_launch(void* const* d_in, const int* in_sizes, int n_in,
                              void* d_out, int out_size, void* d_ws, size_t ws_size,
                              hipStream_t stream) {
    const float* n_feat = (const float*)d_in[0];
    const int*   src    = (const int*)d_in[1];
    const int*   dst    = (const int*)d_in[2];
    const int*   gid    = (const int*)d_in[3];
    const float* W1     = (const float*)d_in[4];
    const float* b1     = (const float*)d_in[5];
    const float* W2     = (const float*)d_in[6];
    const float* b2     = (const float*)d_in[7];
    const float* W3     = (const float*)d_in[8];
    const float* b3     = (const float*)d_in[9];
    const float* Wf1    = (const float*)d_in[10];
    const float* bf1    = (const float*)d_in[11];
    const float* Wf2    = (const float*)d_in[12];
    const float* bf2    = (const float*)d_in[13];
    const float* gamma  = (const float*)d_in[14];
    const float* beta   = (const float*)d_in[15];
    float* out = (float*)d_out;

    char* ws = (char*)d_ws;
    size_t off = 0;
    auto alloc = [&](size_t bytes) {
        void* p = ws + off;
        off = (off + bytes + 255) & ~(size_t)255;
        return p;
    };
    int* cntD    = (int*)alloc((size_t)NB_EDGE * 256 * 4);
    int* cntS    = (int*)alloc((size_t)NB_EDGE * 256 * 4);
    int* offD    = (int*)alloc((size_t)NB_EDGE * 256 * 4);
    int* offS    = (int*)alloc((size_t)NB_EDGE * 256 * 4);
    int* baseD   = (int*)alloc(257 * 4);
    int* baseS   = (int*)alloc(257 * 4);
    int* indeg   = (int*)alloc((size_t)N_NODES * 4);
    int* outdeg  = (int*)alloc((size_t)N_NODES * 4);
    int* rowptr  = (int*)alloc((size_t)(N_NODES + 1) * 4);
    int* gstart  = (int*)alloc((size_t)(N_GRAPHS + 1) * 4);
    uint2* bufD  = (uint2*)alloc((size_t)N_EDGES * 8);
    int* bufS    = (int*)alloc((size_t)N_EDGES * 4);
    int* csr_src = (int*)alloc((size_t)N_EDGES * 4);
    unsigned short* Xs  = (unsigned short*)alloc((size_t)N_NODES * 128 * 2);
    unsigned short* A   = (unsigned short*)alloc((size_t)N_NODES * 128 * 2);
    unsigned short* B   = (unsigned short*)alloc((size_t)N_NODES * 256 * 2);  // also f32 [N,128]
    unsigned short* W1T = (unsigned short*)alloc((size_t)IN_DIM * HID * 2);
    unsigned short* W2T = (unsigned short*)alloc((size_t)HID * H2 * 2);
    unsigned short* W3T = (unsigned short*)alloc((size_t)H2 * H2 * 2);
    float* Bf32 = (float*)B;   // N*256*2 bytes == N*128*4 bytes

    // preprocessing: zero global atomics
    k1_hist<<<NB_EDGE + CW1_BLOCKS + CW2_BLOCKS + CW3_BLOCKS + BND_BLOCKS, 256, 0, stream>>>(
        src, dst, cntD, cntS, W1, W2, W3, W1T, W2T, W3T, gid, gstart);
    k2_scan<<<1, 256, 0, stream>>>(cntD, cntS, offD, offS, baseD, baseS, rowptr);
    k3_scatter<<<NB_EDGE, 256, 0, stream>>>(src, dst, offD, offS, baseD, baseS, bufD, bufS);
    k45_csr_prescale<<<NBUCK * 2, 256, 0, stream>>>(bufD, baseD, indeg, rowptr, csr_src,
                                                    bufS, baseS, n_feat, outdeg,
                                                    (unsigned int*)Xs);

    const int AGG_GRID = (N_NODES + 3) / 4;
    const int GEMM_GRID = 1024;

    // Layer 1: A = bf16(agg(Xs)·id); B = bf16(relu(A@W1 + b1))  [N,256]
    pull_agg<0><<<AGG_GRID, 256, 0, stream>>>((unsigned int*)Xs, rowptr, csr_src,
                                              indeg, outdeg, nullptr, (unsigned int*)A);
    mfma_gemm<128, 256, 1, false><<<GEMM_GRID, 256, 0, stream>>>(A, W1T, b1, nullptr, B);

    // Layer 2: A = bf16((X1@W2)·od); B = bf16(relu(agg(A)·id + b2)·od)
    mfma_gemm<256, 128, 2, false><<<GEMM_GRID, 256, 0, stream>>>(B, W2T, nullptr, outdeg, A);
    pull_agg<1><<<AGG_GRID, 256, 0, stream>>>((unsigned int*)A, rowptr, csr_src,
                                              indeg, outdeg, b2, (unsigned int*)B);

    // Layer 3: A = bf16(agg(B)·id); Bf32 = relu(A@W3 + b3)  [f32 for pooling accuracy]
    pull_agg<0><<<AGG_GRID, 256, 0, stream>>>((unsigned int*)B, rowptr, csr_src,
                                              indeg, outdeg, nullptr, (unsigned int*)A);
    mfma_gemm<128, 128, 1, true><<<GEMM_GRID, 256, 0, stream>>>(A, W3T, b3, nullptr, Bf32);

    // Readout
    seg_pool<<<N_GRAPHS, 512, 0, stream>>>(Bf32, gstart, out);
    fc_kernel<<<N_GRAPHS, 128, 0, stream>>>(out, gamma, beta, Wf1, bf1, Wf2, bf2,
                                            out + (size_t)N_GRAPHS * H2);
}